// Round 1
// baseline (270.994 us; speedup 1.0000x reference)
//
#include <hip/hip_runtime.h>
#include <math.h>

// B=8, N=2048, Fin=Fout=512, fp32 in/out. bf16 MFMA internally.
// out[n,o] = sum_m exp(adj[n,m]) * (sup[m,o] / D[m]),  D[m] = sum_n exp(adj[n,m])
// p1 is pre-scaled by log2(e) so adj accumulates in log2 domain -> raw v_exp_f32.
#define BB 8
#define NN 2048
#define FF 512
#define LOG2E 1.4426950408889634f

typedef __attribute__((ext_vector_type(8))) short short8;
typedef __attribute__((ext_vector_type(4))) float floatx4;
typedef __attribute__((ext_vector_type(2))) float float2v;
typedef __attribute__((ext_vector_type(2))) __bf16 bf16x2;

__device__ __forceinline__ unsigned short f2bf(float f) {
    union { float f; unsigned u; } v; v.f = f;
    unsigned r = v.u + 0x7FFFu + ((v.u >> 16) & 1u);
    return (unsigned short)(r >> 16);
}

__device__ __forceinline__ float fexp2(float x) {
#if __has_builtin(__builtin_amdgcn_exp2f)
    return __builtin_amdgcn_exp2f(x);
#else
    return __expf(x * 0.69314718056f);
#endif
}

// packed f32x2 -> bf16x2 (v_cvt_pk_bf16_f32 on gfx950), RNE
__device__ __forceinline__ void pk_store(unsigned short* p0, unsigned short* p1,
                                         float a, float b) {
    union { bf16x2 h; unsigned short s[2]; } u;
    float2v v; v.x = a; v.y = b;
    u.h = __builtin_convertvector(v, bf16x2);
    *p0 = u.s[0]; *p1 = u.s[1];
}

// ---------------------------------------------------------------------------
// BT-GEMM, bf16 MFMA: C[i,j] = sum_k A[i*a_ld+k] * B[j*b_ld+k]
// Tile BM=256 x BN_T (256 or 128), BK=32, 512 threads = 8 waves (2 Mx4 N).
// Per-wave output 128 x (BN_T/4); acc[8][NR] of 16x16 frags.
// TRIPLE-buffered LDS (96/72 KB): stage K-tile t+2 while computing t.
// Counted vmcnt (never 0 in steady state) + raw s_barrier + setprio(T5).
// LDS layout: 16B chunk (r,k8) -> line L=r>>1, slot = (k8 | ((r&1)<<2)) ^ (L&7).
//   Row stride is 64B (16 banks), so row parity is folded into the slot index:
//   each consecutive-8-lane group of a ds_read_b128 hits 8 distinct 16B slots
//   (verified by enumeration for all quads) -> conflict-free, same family as
//   the previously-verified 0-conflict BK=64 swizzle.
// Staging: global_load_lds writes chunks linearly; source address pre-applies
//   the inverse swizzle (m173 pattern).
// modes: 0 = fp32 out + bias[j]; 1 = bf16 out; 2 = bf16 exp2(out) + Dsum colsum
// ---------------------------------------------------------------------------
template<int BN_T, int MODE>
__global__ __launch_bounds__(512, 2) void gemm256_bt(
    const unsigned short* __restrict__ A, const unsigned short* __restrict__ B,
    void* __restrict__ Cv, const float* __restrict__ bias, float* __restrict__ Dsum,
    int M, int Nc, int K, int a_ld, int b_ld, int ldc,
    long a_batch, long b_batch, long c_batch)
{
    constexpr int NR    = BN_T / 64;      // n-frags per wave (4 or 2)
    constexpr int B_ISS = BN_T / 128;     // B stage issues per K-tile (2 or 1)

    __shared__ __align__(16) unsigned short Alds[3][256 * 32];
    __shared__ __align__(16) unsigned short Blds[3][BN_T * 32];

    const int tid  = threadIdx.x;
    const int wave = tid >> 6;
    const int lane = tid & 63;
    const int wr   = wave >> 2;          // 0..1 (M)
    const int wc   = wave & 3;           // 0..3 (N)
    const int fl   = lane & 15;
    const int quad = lane >> 4;
    const int bz   = blockIdx.z;

    const int m0 = blockIdx.y * 256;
    const int n0 = blockIdx.x * BN_T;

    const unsigned short* Aptr = A + (long)bz * a_batch + (long)m0 * a_ld;
    const unsigned short* Bptr = B + (long)bz * b_batch + (long)n0 * b_ld;

    // loop-invariant staging source offsets (elements); chunk_lin = issue*512+tid
    int offA[2], offB[B_ISS];
    #pragma unroll
    for (int i = 0; i < 2; ++i) {
        const int cl = i * 512 + tid;
        const int L = cl >> 3, s = cl & 7;
        const int cc = s ^ (L & 7);
        offA[i] = (2 * L + (cc >> 2)) * a_ld + (cc & 3) * 8;
    }
    #pragma unroll
    for (int i = 0; i < B_ISS; ++i) {
        const int cl = i * 512 + tid;
        const int L = cl >> 3, s = cl & 7;
        const int cc = s ^ (L & 7);
        offB[i] = (2 * L + (cc >> 2)) * b_ld + (cc & 3) * 8;
    }

    // ds_read addressing: row = rowbase + fl, k8 = quad
    // L&7 == fl>>1 for all frags (row bases are multiples of 16)
    const int slot = (quad | ((fl & 1) << 2)) ^ (fl >> 1);
    const int aRd  = (wr * 64 + (fl >> 1)) * 64 + slot * 8;             // elems
    const int bRd  = (wc * (BN_T / 8) + (fl >> 1)) * 64 + slot * 8;     // elems

    auto STAGE = [&](int buf, const unsigned short* Ap, const unsigned short* Bp) {
        #pragma unroll
        for (int i = 0; i < 2; ++i)
            __builtin_amdgcn_global_load_lds(
                (const __attribute__((address_space(1))) void*)(Ap + offA[i]),
                (__attribute__((address_space(3))) void*)&Alds[buf][(i * 512 + tid) * 8],
                16, 0, 0);
        #pragma unroll
        for (int i = 0; i < B_ISS; ++i)
            __builtin_amdgcn_global_load_lds(
                (const __attribute__((address_space(1))) void*)(Bp + offB[i]),
                (__attribute__((address_space(3))) void*)&Blds[buf][(i * 512 + tid) * 8],
                16, 0, 0);
    };

    floatx4 acc[8][NR] = {};

    const int nt = K >> 5;               // K-tiles of 32 (>= 3 for all our GEMMs)
    // prologue: stage K-tiles 0,1 into buffers 0,1
    STAGE(0, Aptr, Bptr);
    STAGE(1, Aptr + 32, Bptr + 32);
    const unsigned short* Ast = Aptr + 64;
    const unsigned short* Bst = Bptr + 64;
    int rd = 0, st = 2;

    for (int t = 0; t < nt; ++t) {
        // stage K-tile t+2 into buffer st (= last read at t-1; freed by the
        // end-barrier of iteration t-1). Then drain K-tile t's loads only:
        // per-wave outstanding after stage = 3*LPK -> wait to 2*LPK.
        if (t + 2 < nt) {
            STAGE(st, Ast, Bst);
            Ast += 32; Bst += 32;
            if constexpr (BN_T == 256) asm volatile("s_waitcnt vmcnt(8)" ::: "memory");
            else                       asm volatile("s_waitcnt vmcnt(6)" ::: "memory");
        } else if (t + 2 == nt) {
            if constexpr (BN_T == 256) asm volatile("s_waitcnt vmcnt(4)" ::: "memory");
            else                       asm volatile("s_waitcnt vmcnt(3)" ::: "memory");
        } else {
            asm volatile("s_waitcnt vmcnt(0)" ::: "memory");
        }
        __builtin_amdgcn_sched_barrier(0);
        __builtin_amdgcn_s_barrier();        // all waves' t-loads have landed
        __builtin_amdgcn_sched_barrier(0);

        const unsigned short* Ab = Alds[rd];
        const unsigned short* Bb = Blds[rd];
        short8 af[8], bfr[NR];
        #pragma unroll
        for (int m = 0; m < 8; ++m)
            af[m] = *(const short8*)&Ab[aRd + m * 512];
        #pragma unroll
        for (int n = 0; n < NR; ++n)
            bfr[n] = *(const short8*)&Bb[bRd + n * 512];

        __builtin_amdgcn_s_setprio(1);
        #pragma unroll
        for (int m = 0; m < 8; ++m)
            #pragma unroll
            for (int n = 0; n < NR; ++n)
                acc[m][n] = __builtin_amdgcn_mfma_f32_16x16x32_bf16(af[m], bfr[n], acc[m][n], 0, 0, 0);
        __builtin_amdgcn_s_setprio(0);

        __builtin_amdgcn_sched_barrier(0);
        __builtin_amdgcn_s_barrier();        // all waves done reading buf rd
        __builtin_amdgcn_sched_barrier(0);

        rd = (rd == 2) ? 0 : rd + 1;
        st = (st == 2) ? 0 : st + 1;
    }

    // Epilogue: row mg = m0 + wr*128 + m*16 + quad*4 + r; col ng = n0 + wc*(BN_T/4) + n*16 + fl
    const int wmg = m0 + wr * 128;
    const int wng = n0 + wc * (BN_T / 4);

    if constexpr (MODE == 0) {
        float* Cb = (float*)Cv + (long)bz * c_batch;
        #pragma unroll
        for (int n = 0; n < NR; ++n) {
            const int ng = wng + n * 16 + fl;
            const float badd = bias ? bias[ng] : 0.0f;
            #pragma unroll
            for (int m = 0; m < 8; ++m) {
                const int mg = wmg + m * 16 + quad * 4;
                #pragma unroll
                for (int r = 0; r < 4; ++r)
                    Cb[(long)(mg + r) * ldc + ng] = acc[m][n][r] + badd;
            }
        }
    } else if constexpr (MODE == 1) {
        unsigned short* Cb = (unsigned short*)Cv + (long)bz * c_batch;
        #pragma unroll
        for (int n = 0; n < NR; ++n) {
            const int ng = wng + n * 16 + fl;
            #pragma unroll
            for (int m = 0; m < 8; ++m) {
                const int mg = wmg + m * 16 + quad * 4;
                pk_store(&Cb[(long)(mg + 0) * ldc + ng], &Cb[(long)(mg + 1) * ldc + ng],
                         acc[m][n][0], acc[m][n][1]);
                pk_store(&Cb[(long)(mg + 2) * ldc + ng], &Cb[(long)(mg + 3) * ldc + ng],
                         acc[m][n][2], acc[m][n][3]);
            }
        }
    } else {
        // mode 2: acc is log2-domain; E = 2^acc bf16; Dsum[col] += column sums.
        unsigned short* Cb = (unsigned short*)Cv + (long)bz * c_batch;
        float* Db = Dsum + (long)bz * NN;
        #pragma unroll
        for (int m = 0; m < 8; ++m)
            #pragma unroll
            for (int n = 0; n < NR; ++n)
                #pragma unroll
                for (int r = 0; r < 4; ++r)
                    acc[m][n][r] = fexp2(acc[m][n][r]);
        #pragma unroll
        for (int n = 0; n < NR; ++n) {
            const int ng = wng + n * 16 + fl;
            float csum = 0.f;
            #pragma unroll
            for (int m = 0; m < 8; ++m) {
                const int mg = wmg + m * 16 + quad * 4;
                csum += acc[m][n][0] + acc[m][n][1] + acc[m][n][2] + acc[m][n][3];
                pk_store(&Cb[(long)(mg + 0) * ldc + ng], &Cb[(long)(mg + 1) * ldc + ng],
                         acc[m][n][0], acc[m][n][1]);
                pk_store(&Cb[(long)(mg + 2) * ldc + ng], &Cb[(long)(mg + 3) * ldc + ng],
                         acc[m][n][2], acc[m][n][3]);
            }
            csum += __shfl_xor(csum, 16);
            csum += __shfl_xor(csum, 32);
            if (quad == 0) atomicAdd(&Db[ng], csum);
        }
    }
}

// fused fp32->bf16 convert for x, w_one (scaled by log2e), w_two
__global__ __launch_bounds__(256) void convert_all(
    const float* __restrict__ x, const float* __restrict__ w1, const float* __restrict__ w2,
    unsigned short* __restrict__ xb, unsigned short* __restrict__ w1b, unsigned short* __restrict__ w2b)
{
    const long NX = (long)BB * NN * FF / 8;
    const long NW = (long)FF * FF / 8;
    long t = (long)blockIdx.x * 256 + threadIdx.x;
    const float* in; unsigned short* out; float sc = 1.0f;
    if (t < NX) { in = x; out = xb; }
    else if (t < NX + NW) { in = w1; out = w1b; t -= NX; sc = LOG2E; }
    else if (t < NX + 2 * NW) { in = w2; out = w2b; t -= NX + NW; }
    else return;
    const long i = t * 8;
    float4 a = *(const float4*)(in + i);
    float4 b = *(const float4*)(in + i + 4);
    union { bf16x2 h[4]; short8 s8; } u;
    float2v v;
    v.x = a.x * sc; v.y = a.y * sc; u.h[0] = __builtin_convertvector(v, bf16x2);
    v.x = a.z * sc; v.y = a.w * sc; u.h[1] = __builtin_convertvector(v, bf16x2);
    v.x = b.x * sc; v.y = b.y * sc; u.h[2] = __builtin_convertvector(v, bf16x2);
    v.x = b.z * sc; v.y = b.w * sc; u.h[3] = __builtin_convertvector(v, bf16x2);
    *(short8*)(out + i) = u.s8;
}

// out[o,f] = bf16(in[f,o]) for dim x dim fp32 (dim % 32 == 0)
__global__ __launch_bounds__(256) void transpose_convert(
    const float* __restrict__ in, unsigned short* __restrict__ out, int dim)
{
    __shared__ float t[32][33];
    const int tx = threadIdx.x & 31, ty = threadIdx.x >> 5;
    const int x0 = blockIdx.x * 32, y0 = blockIdx.y * 32;
    #pragma unroll
    for (int k = 0; k < 32; k += 8)
        t[ty + k][tx] = in[(long)(y0 + ty + k) * dim + x0 + tx];
    __syncthreads();
    #pragma unroll
    for (int k = 0; k < 32; k += 8)
        out[(long)(x0 + ty + k) * dim + y0 + tx] = f2bf(t[tx][ty + k]);
}

__global__ __launch_bounds__(256) void zero_f32(float* __restrict__ p, long n)
{
    long i = (long)blockIdx.x * 256 + threadIdx.x;
    if (i < n) p[i] = 0.0f;
}

// supT[o,m] = bf16( sup[m,o] / D[m] ); sup[m,o] = Call[m*1536 + 1024 + o] (bf16).
__global__ __launch_bounds__(256) void scale_transpose(
    const unsigned short* __restrict__ Call, const float* __restrict__ D,
    unsigned short* __restrict__ supT, int batch0)
{
    __shared__ float t[32][33];
    __shared__ float rD[32];
    const int tx = threadIdx.x & 31, ty = threadIdx.x >> 5;
    const int mt = blockIdx.x * 32, ot = blockIdx.y * 32;
    const int b = batch0 + blockIdx.z;
    const unsigned short* Cb = Call + (long)b * NN * 1536;
    unsigned short* Tb = supT + (long)b * NN * FF;
    if (threadIdx.x < 32) rD[threadIdx.x] = 1.0f / D[(long)b * NN + mt + threadIdx.x];
    __syncthreads();
    #pragma unroll
    for (int k = 0; k < 32; k += 8) {
        unsigned short u = Cb[(long)(mt + ty + k) * 1536 + 1024 + ot + tx];
        union { unsigned uu; float f; } cv; cv.uu = ((unsigned)u) << 16;
        t[ty + k][tx] = cv.f;
    }
    __syncthreads();
    #pragma unroll
    for (int k = 0; k < 32; k += 8)
        Tb[(long)(ot + ty + k) * NN + mt + tx] = f2bf(t[tx][ty + k] * rD[tx]);
}

extern "C" void kernel_launch(void* const* d_in, const int* in_sizes, int n_in,
                              void* d_out, int out_size, void* d_ws, size_t ws_size,
                              hipStream_t stream)
{
    const float* x      = (const float*)d_in[0];
    const float* weight = (const float*)d_in[1];
    const float* bias   = (const float*)d_in[2];
    const float* w_one  = (const float*)d_in[3];
    const float* w_two  = (const float*)d_in[4];
    float* out = (float*)d_out;

    const long NF  = (long)NN * FF;      // 1,048,576
    const long NN2 = (long)NN * NN;      // 4,194,304
    const long CROW = 1536;              // C_all row stride (p1|p2|sup)

    // workspace carve
    char* p = (char*)d_ws;
    unsigned short* xb    = (unsigned short*)p; p += (size_t)BB * NF * 2;          // 16 MB
    unsigned short* Wall  = (unsigned short*)p; p += (size_t)CROW * FF * 2;        // 1.5 MB
    unsigned short* Call  = (unsigned short*)p; p += (size_t)BB * NN * CROW * 2;   // 48 MB
    unsigned short* supT  = (unsigned short*)p; p += (size_t)BB * NF * 2;          // 16 MB
    float*          Dsum  = (float*)p;          p += (size_t)BB * NN * 4;          // 64 KB
    unsigned short* E     = (unsigned short*)p;                                    // 64 MB (full) or 8 MB (batch)
    unsigned short* w1b = Wall;
    unsigned short* w2b = Wall + (size_t)FF * FF;
    unsigned short* wTb = Wall + (size_t)2 * FF * FF;

    const size_t fixed = (size_t)(p - (char*)d_ws);
    const bool full = ws_size >= fixed + (size_t)BB * NN2 * 2;

    dim3 blk(256), blk5(512);

    // 1) converts (w1 pre-scaled by log2e)
    convert_all<<<dim3(4352), blk, 0, stream>>>(x, w_one, w_two, xb, w1b, w2b);
    transpose_convert<<<dim3(FF / 32, FF / 32), blk, 0, stream>>>(weight, wTb, FF);
    zero_f32<<<dim3((BB * NN) / 256), blk, 0, stream>>>(Dsum, BB * NN);

    // 2) Call[n, e] = x[n,:]·Wall[e,:]   (rows n = A = xb, cols e = B = Wall)
    //    256x128 tile: grid 12 x 8 x 8 = 768 blocks (3 full CU rounds)
    gemm256_bt<128, 1><<<dim3(CROW / 128, NN / 256, BB), blk5, 0, stream>>>(
        xb, Wall, Call, nullptr, nullptr, NN, (int)CROW, FF,
        FF, FF, (int)CROW, NF, 0, NN * CROW);

    if (full) {
        // 3) E[n,m] = exp2(p1·log2e dot p2); Dsum[b,m] += colsums.
        //    256x256 tile: grid 8 x 8 x 8 = 512 blocks (2 full CU rounds)
        gemm256_bt<256, 2><<<dim3(NN / 256, NN / 256, BB), blk5, 0, stream>>>(
            Call, Call + FF, E, nullptr, Dsum, NN, NN, FF,
            (int)CROW, (int)CROW, NN, NN * CROW, NN * CROW, NN2);
        // 4) supT[o,m] = sup[m,o]/D[m]
        scale_transpose<<<dim3(NN / 32, FF / 32, BB), blk, 0, stream>>>(Call, Dsum, supT, 0);
        // 5) out[n,o] = E[n,:]·supT[o,:] + bias[o]
        //    256x128 tile: grid 4 x 8 x 8 = 256 blocks (1 full CU round)
        gemm256_bt<128, 0><<<dim3(FF / 128, NN / 256, BB), blk5, 0, stream>>>(
            E, supT, out, bias, nullptr, NN, FF, NN,
            NN, NN, FF, NN2, NF, NF);
    } else {
        for (int b = 0; b < BB; ++b) {
            const unsigned short* Cb = Call + (size_t)b * NN * CROW;
            gemm256_bt<256, 2><<<dim3(NN / 256, NN / 256, 1), blk5, 0, stream>>>(
                Cb, Cb + FF, E, nullptr, Dsum + (size_t)b * NN, NN, NN, FF,
                (int)CROW, (int)CROW, NN, 0, 0, 0);
            scale_transpose<<<dim3(NN / 32, FF / 32, 1), blk, 0, stream>>>(Call, Dsum, supT, b);
            gemm256_bt<128, 0><<<dim3(FF / 128, NN / 256, 1), blk5, 0, stream>>>(
                E, supT + (size_t)b * NF, out + (size_t)b * NF, bias, nullptr, NN, FF, NN,
                NN, NN, FF, 0, 0, 0);
        }
    }
}

// Round 2
// 249.198 us; speedup vs baseline: 1.0875x; 1.0875x over previous
//
#include <hip/hip_runtime.h>
#include <math.h>

// B=8, N=2048, Fin=Fout=512, fp32 in/out. bf16 MFMA internally.
// out[n,o] = sum_m exp(adj[n,m]) * (sup[m,o] / D[m]),  D[m] = sum_n exp(adj[n,m])
// p1 is pre-scaled by log2(e) so adj accumulates in log2 domain -> raw v_exp_f32.
#define BB 8
#define NN 2048
#define FF 512
#define LOG2E 1.4426950408889634f

typedef __attribute__((ext_vector_type(8))) short short8;
typedef __attribute__((ext_vector_type(4))) float floatx4;
typedef __attribute__((ext_vector_type(2))) float float2v;
typedef __attribute__((ext_vector_type(2))) __bf16 bf16x2;

__device__ __forceinline__ unsigned short f2bf(float f) {
    union { float f; unsigned u; } v; v.f = f;
    unsigned r = v.u + 0x7FFFu + ((v.u >> 16) & 1u);
    return (unsigned short)(r >> 16);
}

__device__ __forceinline__ float fexp2(float x) {
#if __has_builtin(__builtin_amdgcn_exp2f)
    return __builtin_amdgcn_exp2f(x);
#else
    return __expf(x * 0.69314718056f);
#endif
}

__device__ __forceinline__ void pk_store(unsigned short* p0, unsigned short* p1,
                                         float a, float b) {
    union { bf16x2 h; unsigned short s[2]; } u;
    float2v v; v.x = a; v.y = b;
    u.h = __builtin_convertvector(v, bf16x2);
    *p0 = u.s[0]; *p1 = u.s[1];
}

#define BARRIER() do { __builtin_amdgcn_sched_barrier(0); \
                       __builtin_amdgcn_s_barrier(); \
                       __builtin_amdgcn_sched_barrier(0); } while (0)

// ---------------------------------------------------------------------------
// 8-phase BT-GEMM (m194-m201 template port), bf16 MFMA:
//   C[i,j] = sum_k A[i*a_ld+k] * B[j*b_ld+k]
// Tile BM x 256, BM = M_REP*32. 512 thr = 8 waves (2 M x 4 N); per-wave
// output (M_REP*16) x 64, acc[M_REP][4]. BK=64 split into two 32-K halves.
// LDS: per matrix 4 rotating slots [khalf][dbuf] (dbuf = tile parity).
// Iteration i computes tiles (t=2i, t+1); 8 phases, each = {ds_read frags,
// stage ONE half-tile, (vmcnt at ph4/8), barrier, MFMA quadrant, barrier}.
// Stage cadence (steady): ph1 Bk1(t+1) | ph2 Ak0(t+2) | ph3 Bk0(t+2) |
//   ph4 Ak1(t+2)+vmcnt | ph5 Bk1(t+2) | ph6 Ak0(t+3) | ph7 Bk0(t+3) |
//   ph8 Ak1(t+3)+vmcnt.
// Verified invariants (hand-checked):
//  * slot overwrite: each stage at phase p issues after the end-barrier of
//    the slot's last-consumer phase (A-k0 last read ph1/5, B-k0 ph2/6,
//    A-k1 ph3/7, B-k1 ph4/8; stages land exactly one phase later or in the
//    mirror half / next iteration).
//  * vmcnt(2*LA+LB) at ph4 leaves exactly {ph2,ph3,ph4} stages in flight ->
//    drains all of tile t+1's halves (staged prev ph6,7,8 + this ph1) before
//    ph5 reads them; ph8 likewise drains tile t+2 before next-iter ph1.
//  * last iteration: only ph1's stage is issued; ph4 uses vmcnt(0).
// LDS swizzle: row r (32 elems = 64 B, 4 16B chunks), slot s holds global
// chunk c = s ^ ((r>>1)&3); reads use slot quad ^ ((fl>>1)&3). Within each
// 16-lane quarter-wave the 8 distinct 16B positions mod 128B are each hit by
// exactly 2 lanes -> 2-way = free (m136). global_load_lds writes linear,
// source pre-applies the (involutive) swizzle (m173 pattern).
// modes: 0 = fp32 out + bias[j]; 1 = bf16 out; 2 = bf16 exp2(out) + Dsum.
// Requires K % 128 == 0, K >= 256.
// ---------------------------------------------------------------------------
template<int M_REP, int MODE>
__global__ __launch_bounds__(512, 2) void gemm8p(
    const unsigned short* __restrict__ A, const unsigned short* __restrict__ B,
    void* __restrict__ Cv, const float* __restrict__ bias, float* __restrict__ Dsum,
    int K, int a_ld, int b_ld, int ldc,
    long a_batch, long b_batch, long c_batch)
{
    constexpr int BM  = M_REP * 32;
    constexpr int LA  = BM / 128;        // global_load_lds issues per A-half
    constexpr int VMS = 2 * LA + 2;      // steady-state vmcnt

    __shared__ __align__(16) unsigned short Ah[2][2][BM * 32];   // [khalf][dbuf]
    __shared__ __align__(16) unsigned short Bh[2][2][256 * 32];

    const int tid  = threadIdx.x;
    const int wave = tid >> 6;
    const int lane = tid & 63;
    const int wr   = wave >> 2;          // 0..1 (M)
    const int wc   = wave & 3;           // 0..3 (N)
    const int fl   = lane & 15;
    const int quad = lane >> 4;
    const int bz   = blockIdx.z;

    const int m0 = blockIdx.y * BM;
    const int n0 = blockIdx.x * 256;

    const unsigned short* Aptr = A + (long)bz * a_batch + (long)m0 * a_ld;
    const unsigned short* Bptr = B + (long)bz * b_batch + (long)n0 * b_ld;

    // staging source offsets (inverse-swizzled), loop-invariant per thread
    int offA[LA], offB[2];
    #pragma unroll
    for (int i = 0; i < LA; ++i) {
        const int cl = i * 512 + tid;
        const int r = cl >> 2, s = cl & 3;
        offA[i] = r * a_ld + (s ^ ((r >> 1) & 3)) * 8;
    }
    #pragma unroll
    for (int i = 0; i < 2; ++i) {
        const int cl = i * 512 + tid;
        const int r = cl >> 2, s = cl & 3;
        offB[i] = r * b_ld + (s ^ ((r >> 1) & 3)) * 8;
    }

    // ds_read bases (elements): row R = rb + fl, chunk quad ^ ((fl>>1)&3)
    const int swz = (quad ^ ((fl >> 1) & 3)) * 8;
    const int aRd = (wr * (M_REP * 16) + fl) * 32 + swz;
    const int bRd = (wc * 64 + fl) * 32 + swz;

    auto stageA = [&](int kh, int db, int kbase) {
        #pragma unroll
        for (int i = 0; i < LA; ++i)
            __builtin_amdgcn_global_load_lds(
                (const __attribute__((address_space(1))) void*)(Aptr + kbase + offA[i]),
                (__attribute__((address_space(3))) void*)&Ah[kh][db][(i * 512 + tid) * 8],
                16, 0, 0);
    };
    auto stageB = [&](int kh, int db, int kbase) {
        #pragma unroll
        for (int i = 0; i < 2; ++i)
            __builtin_amdgcn_global_load_lds(
                (const __attribute__((address_space(1))) void*)(Bptr + kbase + offB[i]),
                (__attribute__((address_space(3))) void*)&Bh[kh][db][(i * 512 + tid) * 8],
                16, 0, 0);
    };

    floatx4 acc[M_REP][4] = {};
    short8 af[M_REP];
    short8 bf[2];

    auto LOADA = [&](int kh, int db) {
        const unsigned short* base = &Ah[kh][db][aRd];
        #pragma unroll
        for (int m = 0; m < M_REP; ++m)
            af[m] = *(const short8*)(base + m * 512);
    };
    auto LOADB = [&](int kh, int db, int nh) {
        const unsigned short* base = &Bh[kh][db][bRd + nh * 1024];
        bf[0] = *(const short8*)(base);
        bf[1] = *(const short8*)(base + 512);
    };
    auto MFMAQ = [&](int nh) {
        __builtin_amdgcn_s_setprio(1);
        #pragma unroll
        for (int m = 0; m < M_REP; ++m) {
            acc[m][nh * 2]     = __builtin_amdgcn_mfma_f32_16x16x32_bf16(af[m], bf[0], acc[m][nh * 2], 0, 0, 0);
            acc[m][nh * 2 + 1] = __builtin_amdgcn_mfma_f32_16x16x32_bf16(af[m], bf[1], acc[m][nh * 2 + 1], 0, 0, 0);
        }
        __builtin_amdgcn_s_setprio(0);
    };

    const int nt = K >> 6;               // 64-wide K-tiles (even, >= 4)
    const int ni = nt >> 1;

    // prologue: tiles 0,1 minus Bk1(1); oldest 2*LA+4 loads = tile 0 complete
    stageA(0, 0, 0);  stageB(0, 0, 0);  stageA(1, 0, 32);  stageB(1, 0, 32);
    stageA(0, 1, 64); stageB(0, 1, 64); stageA(1, 1, 96);
    if constexpr (VMS == 6) asm volatile("s_waitcnt vmcnt(6)" ::: "memory");
    else                    asm volatile("s_waitcnt vmcnt(4)" ::: "memory");
    BARRIER();

    for (int i = 0; i < ni; ++i) {
        const bool last = (i == ni - 1);
        const int kb1 = (2 * i + 1) * 64;
        const int kb2 = (2 * i + 2) * 64;
        const int kb3 = (2 * i + 3) * 64;

        // ph1: Q(t, k0, n01); stage Bk1(t+1)
        LOADA(0, 0); LOADB(0, 0, 0);
        stageB(1, 1, kb1 + 32);
        BARRIER(); MFMAQ(0); BARRIER();

        // ph2: Q(t, k0, n23); stage Ak0(t+2)
        LOADB(0, 0, 1);
        if (!last) stageA(0, 0, kb2);
        BARRIER(); MFMAQ(1); BARRIER();

        // ph3: Q(t, k1, n01); stage Bk0(t+2)
        LOADA(1, 0); LOADB(1, 0, 0);
        if (!last) stageB(0, 0, kb2);
        BARRIER(); MFMAQ(0); BARRIER();

        // ph4: Q(t, k1, n23); stage Ak1(t+2); drain tile t+1
        LOADB(1, 0, 1);
        if (!last) {
            stageA(1, 0, kb2 + 32);
            if constexpr (VMS == 6) asm volatile("s_waitcnt vmcnt(6)" ::: "memory");
            else                    asm volatile("s_waitcnt vmcnt(4)" ::: "memory");
        } else {
            asm volatile("s_waitcnt vmcnt(0)" ::: "memory");
        }
        BARRIER(); MFMAQ(1); BARRIER();

        // ph5: Q(t+1, k0, n01); stage Bk1(t+2)
        LOADA(0, 1); LOADB(0, 1, 0);
        if (!last) stageB(1, 0, kb2 + 32);
        BARRIER(); MFMAQ(0); BARRIER();

        // ph6: Q(t+1, k0, n23); stage Ak0(t+3)
        LOADB(0, 1, 1);
        if (!last) stageA(0, 1, kb3);
        BARRIER(); MFMAQ(1); BARRIER();

        // ph7: Q(t+1, k1, n01); stage Bk0(t+3)
        LOADA(1, 1); LOADB(1, 1, 0);
        if (!last) stageB(0, 1, kb3);
        BARRIER(); MFMAQ(0); BARRIER();

        // ph8: Q(t+1, k1, n23); stage Ak1(t+3); drain tile t+2
        LOADB(1, 1, 1);
        if (!last) {
            stageA(1, 1, kb3 + 32);
            if constexpr (VMS == 6) asm volatile("s_waitcnt vmcnt(6)" ::: "memory");
            else                    asm volatile("s_waitcnt vmcnt(4)" ::: "memory");
        }
        BARRIER(); MFMAQ(1); BARRIER();
    }

    // Epilogue: row = m0 + wr*(M_REP*16) + m*16 + quad*4 + r; col = n0 + wc*64 + n*16 + fl
    const int wmg = m0 + wr * (M_REP * 16);
    const int wng = n0 + wc * 64;

    if constexpr (MODE == 0) {
        float* Cb = (float*)Cv + (long)bz * c_batch;
        #pragma unroll
        for (int n = 0; n < 4; ++n) {
            const int ng = wng + n * 16 + fl;
            const float badd = bias ? bias[ng] : 0.0f;
            #pragma unroll
            for (int m = 0; m < M_REP; ++m) {
                const int mg = wmg + m * 16 + quad * 4;
                #pragma unroll
                for (int r = 0; r < 4; ++r)
                    Cb[(long)(mg + r) * ldc + ng] = acc[m][n][r] + badd;
            }
        }
    } else if constexpr (MODE == 1) {
        unsigned short* Cb = (unsigned short*)Cv + (long)bz * c_batch;
        #pragma unroll
        for (int n = 0; n < 4; ++n) {
            const int ng = wng + n * 16 + fl;
            #pragma unroll
            for (int m = 0; m < M_REP; ++m) {
                const int mg = wmg + m * 16 + quad * 4;
                pk_store(&Cb[(long)(mg + 0) * ldc + ng], &Cb[(long)(mg + 1) * ldc + ng],
                         acc[m][n][0], acc[m][n][1]);
                pk_store(&Cb[(long)(mg + 2) * ldc + ng], &Cb[(long)(mg + 3) * ldc + ng],
                         acc[m][n][2], acc[m][n][3]);
            }
        }
    } else {
        // mode 2: acc is log2-domain; E = 2^acc bf16; Dsum[col] += column sums.
        unsigned short* Cb = (unsigned short*)Cv + (long)bz * c_batch;
        float* Db = Dsum + (long)bz * NN;
        #pragma unroll
        for (int m = 0; m < M_REP; ++m)
            #pragma unroll
            for (int n = 0; n < 4; ++n)
                #pragma unroll
                for (int r = 0; r < 4; ++r)
                    acc[m][n][r] = fexp2(acc[m][n][r]);
        #pragma unroll
        for (int n = 0; n < 4; ++n) {
            const int ng = wng + n * 16 + fl;
            float csum = 0.f;
            #pragma unroll
            for (int m = 0; m < M_REP; ++m) {
                const int mg = wmg + m * 16 + quad * 4;
                csum += acc[m][n][0] + acc[m][n][1] + acc[m][n][2] + acc[m][n][3];
                pk_store(&Cb[(long)(mg + 0) * ldc + ng], &Cb[(long)(mg + 1) * ldc + ng],
                         acc[m][n][0], acc[m][n][1]);
                pk_store(&Cb[(long)(mg + 2) * ldc + ng], &Cb[(long)(mg + 3) * ldc + ng],
                         acc[m][n][2], acc[m][n][3]);
            }
            csum += __shfl_xor(csum, 16);
            csum += __shfl_xor(csum, 32);
            if (quad == 0) atomicAdd(&Db[ng], csum);
        }
    }
}

// fused fp32->bf16 convert for x, w_one (scaled by log2e), w_two
__global__ __launch_bounds__(256) void convert_all(
    const float* __restrict__ x, const float* __restrict__ w1, const float* __restrict__ w2,
    unsigned short* __restrict__ xb, unsigned short* __restrict__ w1b, unsigned short* __restrict__ w2b)
{
    const long NX = (long)BB * NN * FF / 8;
    const long NW = (long)FF * FF / 8;
    long t = (long)blockIdx.x * 256 + threadIdx.x;
    const float* in; unsigned short* out; float sc = 1.0f;
    if (t < NX) { in = x; out = xb; }
    else if (t < NX + NW) { in = w1; out = w1b; t -= NX; sc = LOG2E; }
    else if (t < NX + 2 * NW) { in = w2; out = w2b; t -= NX + NW; }
    else return;
    const long i = t * 8;
    float4 a = *(const float4*)(in + i);
    float4 b = *(const float4*)(in + i + 4);
    union { bf16x2 h[4]; short8 s8; } u;
    float2v v;
    v.x = a.x * sc; v.y = a.y * sc; u.h[0] = __builtin_convertvector(v, bf16x2);
    v.x = a.z * sc; v.y = a.w * sc; u.h[1] = __builtin_convertvector(v, bf16x2);
    v.x = b.x * sc; v.y = b.y * sc; u.h[2] = __builtin_convertvector(v, bf16x2);
    v.x = b.z * sc; v.y = b.w * sc; u.h[3] = __builtin_convertvector(v, bf16x2);
    *(short8*)(out + i) = u.s8;
}

// out[o,f] = bf16(in[f,o]) for dim x dim fp32 (dim % 32 == 0)
__global__ __launch_bounds__(256) void transpose_convert(
    const float* __restrict__ in, unsigned short* __restrict__ out, int dim)
{
    __shared__ float t[32][33];
    const int tx = threadIdx.x & 31, ty = threadIdx.x >> 5;
    const int x0 = blockIdx.x * 32, y0 = blockIdx.y * 32;
    #pragma unroll
    for (int k = 0; k < 32; k += 8)
        t[ty + k][tx] = in[(long)(y0 + ty + k) * dim + x0 + tx];
    __syncthreads();
    #pragma unroll
    for (int k = 0; k < 32; k += 8)
        out[(long)(x0 + ty + k) * dim + y0 + tx] = f2bf(t[tx][ty + k]);
}

__global__ __launch_bounds__(256) void zero_f32(float* __restrict__ p, long n)
{
    long i = (long)blockIdx.x * 256 + threadIdx.x;
    if (i < n) p[i] = 0.0f;
}

// supT[o,m] = bf16( sup[m,o] / D[m] ); sup[m,o] = Call[m*1536 + 1024 + o] (bf16).
__global__ __launch_bounds__(256) void scale_transpose(
    const unsigned short* __restrict__ Call, const float* __restrict__ D,
    unsigned short* __restrict__ supT, int batch0)
{
    __shared__ float t[32][33];
    __shared__ float rD[32];
    const int tx = threadIdx.x & 31, ty = threadIdx.x >> 5;
    const int mt = blockIdx.x * 32, ot = blockIdx.y * 32;
    const int b = batch0 + blockIdx.z;
    const unsigned short* Cb = Call + (long)b * NN * 1536;
    unsigned short* Tb = supT + (long)b * NN * FF;
    if (threadIdx.x < 32) rD[threadIdx.x] = 1.0f / D[(long)b * NN + mt + threadIdx.x];
    __syncthreads();
    #pragma unroll
    for (int k = 0; k < 32; k += 8) {
        unsigned short u = Cb[(long)(mt + ty + k) * 1536 + 1024 + ot + tx];
        union { unsigned uu; float f; } cv; cv.uu = ((unsigned)u) << 16;
        t[ty + k][tx] = cv.f;
    }
    __syncthreads();
    #pragma unroll
    for (int k = 0; k < 32; k += 8)
        Tb[(long)(ot + ty + k) * NN + mt + tx] = f2bf(t[tx][ty + k] * rD[tx]);
}

extern "C" void kernel_launch(void* const* d_in, const int* in_sizes, int n_in,
                              void* d_out, int out_size, void* d_ws, size_t ws_size,
                              hipStream_t stream)
{
    const float* x      = (const float*)d_in[0];
    const float* weight = (const float*)d_in[1];
    const float* bias   = (const float*)d_in[2];
    const float* w_one  = (const float*)d_in[3];
    const float* w_two  = (const float*)d_in[4];
    float* out = (float*)d_out;

    const long NF  = (long)NN * FF;      // 1,048,576
    const long NN2 = (long)NN * NN;      // 4,194,304
    const long CROW = 1536;              // C_all row stride (p1|p2|sup)

    // workspace carve
    char* p = (char*)d_ws;
    unsigned short* xb    = (unsigned short*)p; p += (size_t)BB * NF * 2;          // 16 MB
    unsigned short* Wall  = (unsigned short*)p; p += (size_t)CROW * FF * 2;        // 1.5 MB
    unsigned short* Call  = (unsigned short*)p; p += (size_t)BB * NN * CROW * 2;   // 48 MB
    unsigned short* supT  = (unsigned short*)p; p += (size_t)BB * NF * 2;          // 16 MB
    float*          Dsum  = (float*)p;          p += (size_t)BB * NN * 4;          // 64 KB
    unsigned short* E     = (unsigned short*)p;                                    // 64 MB (full) or 8 MB (batch)
    unsigned short* w1b = Wall;
    unsigned short* w2b = Wall + (size_t)FF * FF;
    unsigned short* wTb = Wall + (size_t)2 * FF * FF;

    const size_t fixed = (size_t)(p - (char*)d_ws);
    const bool full = ws_size >= fixed + (size_t)BB * NN2 * 2;

    dim3 blk(256), blk5(512);

    // 1) converts (w1 pre-scaled by log2e)
    convert_all<<<dim3(4352), blk, 0, stream>>>(x, w_one, w_two, xb, w1b, w2b);
    transpose_convert<<<dim3(FF / 32, FF / 32), blk, 0, stream>>>(weight, wTb, FF);
    zero_f32<<<dim3((BB * NN) / 256), blk, 0, stream>>>(Dsum, BB * NN);

    // 2) Call[n, e] = x[n,:]·Wall[e,:]  — 128x256 tile, 6 x 16 x 8 = 768 blocks
    gemm8p<4, 1><<<dim3(CROW / 256, NN / 128, BB), blk5, 0, stream>>>(
        xb, Wall, Call, nullptr, nullptr, FF,
        FF, FF, (int)CROW, NF, 0, NN * CROW);

    if (full) {
        // 3) E[n,m] = exp2(p1·log2e dot p2); Dsum[b,m] += colsums.
        //    256x256 tile: 8 x 8 x 8 = 512 blocks
        gemm8p<8, 2><<<dim3(NN / 256, NN / 256, BB), blk5, 0, stream>>>(
            Call, Call + FF, E, nullptr, Dsum, FF,
            (int)CROW, (int)CROW, NN, NN * CROW, NN * CROW, NN2);
        // 4) supT[o,m] = sup[m,o]/D[m]
        scale_transpose<<<dim3(NN / 32, FF / 32, BB), blk, 0, stream>>>(Call, Dsum, supT, 0);
        // 5) out[n,o] = E[n,:]·supT[o,:] + bias[o] — 128x256 tile, 2 x 16 x 8 = 256 blocks
        gemm8p<4, 0><<<dim3(FF / 256, NN / 128, BB), blk5, 0, stream>>>(
            E, supT, out, bias, nullptr, NN,
            NN, NN, FF, NN2, NF, NF);
    } else {
        for (int b = 0; b < BB; ++b) {
            const unsigned short* Cb = Call + (size_t)b * NN * CROW;
            gemm8p<8, 2><<<dim3(NN / 256, NN / 256, 1), blk5, 0, stream>>>(
                Cb, Cb + FF, E, nullptr, Dsum + (size_t)b * NN, FF,
                (int)CROW, (int)CROW, NN, 0, 0, 0);
            scale_transpose<<<dim3(NN / 32, FF / 32, 1), blk, 0, stream>>>(Call, Dsum, supT, b);
            gemm8p<4, 0><<<dim3(FF / 256, NN / 128, 1), blk5, 0, stream>>>(
                E, supT + (size_t)b * NF, out + (size_t)b * NF, bias, nullptr, NN,
                NN, NN, FF, 0, 0, 0);
        }
    }
}

// Round 4
// 248.039 us; speedup vs baseline: 1.0925x; 1.0047x over previous
//
#include <hip/hip_runtime.h>
#include <math.h>

// B=8, N=2048, Fin=Fout=512, fp32 in/out. bf16 MFMA internally.
// out[n,o] = sum_m exp(adj[n,m]) * (sup[m,o] / D[m]),  D[m] = sum_n exp(adj[n,m])
// p1 is pre-scaled by log2(e) so adj accumulates in log2 domain -> raw v_exp_f32.
#define BB 8
#define NN 2048
#define FF 512
#define LOG2E 1.4426950408889634f

typedef __attribute__((ext_vector_type(8))) short short8;
typedef __attribute__((ext_vector_type(4))) float floatx4;
typedef __attribute__((ext_vector_type(2))) float float2v;
typedef __attribute__((ext_vector_type(2))) __bf16 bf16x2;

__device__ __forceinline__ unsigned short f2bf(float f) {
    union { float f; unsigned u; } v; v.f = f;
    unsigned r = v.u + 0x7FFFu + ((v.u >> 16) & 1u);
    return (unsigned short)(r >> 16);
}

__device__ __forceinline__ float fexp2(float x) {
#if __has_builtin(__builtin_amdgcn_exp2f)
    return __builtin_amdgcn_exp2f(x);
#else
    return __expf(x * 0.69314718056f);
#endif
}

#define SB0() __builtin_amdgcn_sched_barrier(0)
#define BARRIER() do { SB0(); __builtin_amdgcn_s_barrier(); SB0(); } while (0)
#define GLDS(src, dst) __builtin_amdgcn_global_load_lds( \
    (const __attribute__((address_space(1))) void*)(src), \
    (__attribute__((address_space(3))) void*)(dst), 16, 0, 0)
#define VMW(n) asm volatile("s_waitcnt vmcnt(" #n ")" ::: "memory")

// ---------------------------------------------------------------------------
// 8-phase BT-GEMM with one-phase register read-ahead.
//   C[i,j] = sum_k A[i*a_ld+k] * B[j*b_ld+k]
// Tile BM x 256 (BM = M_REP*32), 256 thr = 4 waves (2M x 2N); per-wave output
// (M_REP*16) x 128, acc[M_REP][8]. BK=64 split in two 32-k halves; LDS holds
// 4 rotating slots per matrix [khalf][tile-parity].
// Phase p: [stage one half-tile][vmcnt@ph4/8][barrier][issue ds_reads for
// phase p+1 into the ALTERNATE reg set][sched0][MFMA cluster p][barrier].
// Reads drain under the previous cluster's MFMAs (read-ahead); counted
// vmcnt(2*LA+4) never drains to 0 mid-loop (T4); setprio around MFMA (T5).
// Schedule invariants hand-verified:
//  * publish: R(5)/R(1') issue strictly after the ph4/ph8 vmcnt+barrier that
//    drains their tile.
//  * overwrite: every stage S(q) issues after barrier B2(q-1); all reads of
//    the slot S(q) overwrites were lgkm-drained before their wave's B2(q-1).
//  * ph4 vmcnt leaves exactly {ph2,ph3,ph4} stages in flight -> tile t+1
//    fully resident before ph5; ph8 likewise for tile t+2.
// LDS swizzle (verified conflict-free family, r2: 0 conflicts): row r holds
// global 16B chunk c at slot c ^ ((r>>1)&3); reads use slot quad^((fl>>1)&3).
// Epilogue (modes 1/2): restage tile in LDS (col ^ (quad<<4) swizzle, 2-way
// max) then coalesced short8 readout + dwordx4 stores — kills the 2.1x HBM
// write amplification of scattered 2B stores (r2: WRITE_SIZE 136MB vs 64).
// XCD swizzle: flat-bijective (nwg%8==0 for all grids) -> batch-per-XCD,
// A/B panels L2-resident.
// modes: 0 = fp32 out + bias[j]; 1 = bf16 out; 2 = bf16 exp2(out) + Dsum.
// Requires K % 128 == 0, K >= 256.
// ---------------------------------------------------------------------------
template<int M_REP, int MODE>
__global__ __launch_bounds__(256, 1) void gemm8p(
    const unsigned short* __restrict__ A, const unsigned short* __restrict__ B,
    void* __restrict__ Cv, const float* __restrict__ bias, float* __restrict__ Dsum,
    int K, int a_ld, int b_ld, int ldc,
    long a_batch, long b_batch, long c_batch)
{
    constexpr int BM    = M_REP * 32;
    constexpr int LA    = BM / 64;           // A-half global_load_lds issues
    constexpr int ASLOT = BM * 32;           // elems per A slot
    constexpr int BSLOT = 256 * 32;
    constexpr int BBASE = 4 * ASLOT;
    constexpr int TOT   = 4 * ASLOT + 4 * BSLOT;

    __shared__ __align__(16) unsigned short SH[TOT];

    const int tid  = threadIdx.x;
    const int wave = tid >> 6;
    const int lane = tid & 63;
    const int wr   = wave >> 1;              // 0..1 (M)
    const int wc   = wave & 1;               // 0..1 (N)
    const int fl   = lane & 15;
    const int quad = lane >> 4;

    // XCD-bijective block swizzle: batch -> one XCD (L2-resident panels)
    const int gx = gridDim.x, gy = gridDim.y;
    int flat = blockIdx.x + gx * (blockIdx.y + gy * blockIdx.z);
    const int cpx = (gx * gy * gridDim.z) >> 3;
    flat = (flat & 7) * cpx + (flat >> 3);
    const int bx = flat % gx;
    const int rest = flat / gx;
    const int by = rest % gy;
    const int bz = rest / gy;

    const int m0 = by * BM;
    const int n0 = bx * 256;

    const unsigned short* Aptr = A + (long)bz * a_batch + (long)m0 * a_ld;
    const unsigned short* Bptr = B + (long)bz * b_batch + (long)n0 * b_ld;

    // staging source offsets (inverse-swizzled), loop-invariant
    int offA[LA], offB[4];
    #pragma unroll
    for (int i = 0; i < LA; ++i) {
        const int cl = i * 256 + tid;
        const int r = cl >> 2, s = cl & 3;
        offA[i] = r * a_ld + (s ^ ((r >> 1) & 3)) * 8;
    }
    #pragma unroll
    for (int i = 0; i < 4; ++i) {
        const int cl = i * 256 + tid;
        const int r = cl >> 2, s = cl & 3;
        offB[i] = r * b_ld + (s ^ ((r >> 1) & 3)) * 8;
    }

    // fragment ds_read bases (elems): row = base+fl, chunk = quad^((fl>>1)&3)
    const int swz = (quad ^ ((fl >> 1) & 3)) * 8;
    const int aRd = (wr * (M_REP * 16) + fl) * 32 + swz;
    const int bRd = (wc * 128 + fl) * 32 + swz;

    auto sA = [&](int kh, int db, int kb) {
        #pragma unroll
        for (int i = 0; i < LA; ++i)
            GLDS(Aptr + kb + offA[i], &SH[(kh * 2 + db) * ASLOT + (i * 256 + tid) * 8]);
    };
    auto sB = [&](int kh, int db, int kb) {
        #pragma unroll
        for (int i = 0; i < 4; ++i)
            GLDS(Bptr + kb + offB[i], &SH[BBASE + (kh * 2 + db) * BSLOT + (i * 256 + tid) * 8]);
    };

    floatx4 acc[M_REP][8] = {};
    short8 afA[M_REP], afB[M_REP], bfA[4], bfB[4];

    auto RA = [&](short8* af, int kh, int db) {
        const unsigned short* b = &SH[(kh * 2 + db) * ASLOT + aRd];
        #pragma unroll
        for (int m = 0; m < M_REP; ++m) af[m] = *(const short8*)(b + m * 512);
    };
    auto RB = [&](short8* bf, int kh, int db, int nh) {
        const unsigned short* b = &SH[BBASE + (kh * 2 + db) * BSLOT + bRd + nh * 2048];
        #pragma unroll
        for (int j = 0; j < 4; ++j) bf[j] = *(const short8*)(b + j * 512);
    };
    auto MC = [&](short8* af, short8* bf, int nh) {
        __builtin_amdgcn_s_setprio(1);
        #pragma unroll
        for (int m = 0; m < M_REP; ++m)
            #pragma unroll
            for (int j = 0; j < 4; ++j)
                acc[m][nh * 4 + j] = __builtin_amdgcn_mfma_f32_16x16x32_bf16(af[m], bf[j], acc[m][nh * 4 + j], 0, 0, 0);
        __builtin_amdgcn_s_setprio(0);
    };

    const int nt = K >> 6;
    const int ni = nt >> 1;

    // prologue: tiles 0,1 minus Bk1(1); drain tile 0, leave 3 halves in flight
    sA(0, 0, 0);  sB(0, 0, 0);  sA(1, 0, 32); sB(1, 0, 32);
    sA(0, 1, 64); sB(0, 1, 64); sA(1, 1, 96);
    if constexpr (M_REP == 8) VMW(12); else VMW(8);
    BARRIER();
    RA(afA, 0, 0); RB(bfA, 0, 0, 0);
    SB0();

    for (int i = 0; i < ni; ++i) {
        const bool last = (i == ni - 1);
        const int kb1 = (2 * i + 1) * 64, kb2 = kb1 + 64, kb3 = kb2 + 64;

        // ph1: cluster(t,k0,n01); stage Bk1(t+1)
        sB(1, 1, kb1 + 32);
        BARRIER();
        RB(bfB, 0, 0, 1); SB0();
        MC(afA, bfA, 0);
        BARRIER();
        // ph2: cluster(t,k0,n23); stage Ak0(t+2)
        if (!last) sA(0, 0, kb2);
        BARRIER();
        RA(afB, 1, 0); RB(bfA, 1, 0, 0); SB0();
        MC(afA, bfB, 1);
        BARRIER();
        // ph3: cluster(t,k1,n01); stage Bk0(t+2)
        if (!last) sB(0, 0, kb2);
        BARRIER();
        RB(bfB, 1, 0, 1); SB0();
        MC(afB, bfA, 0);
        BARRIER();
        // ph4: cluster(t,k1,n23); stage Ak1(t+2); drain tile t+1
        if (!last) {
            sA(1, 0, kb2 + 32);
            if constexpr (M_REP == 8) VMW(12); else VMW(8);
        } else {
            VMW(0);
        }
        BARRIER();
        RA(afA, 0, 1); RB(bfA, 0, 1, 0); SB0();
        MC(afB, bfB, 1);
        BARRIER();
        // ph5: cluster(t+1,k0,n01); stage Bk1(t+2)
        if (!last) sB(1, 0, kb2 + 32);
        BARRIER();
        RB(bfB, 0, 1, 1); SB0();
        MC(afA, bfA, 0);
        BARRIER();
        // ph6: cluster(t+1,k0,n23); stage Ak0(t+3)
        if (!last) sA(0, 1, kb3);
        BARRIER();
        RA(afB, 1, 1); RB(bfA, 1, 1, 0); SB0();
        MC(afA, bfB, 1);
        BARRIER();
        // ph7: cluster(t+1,k1,n01); stage Bk0(t+3)
        if (!last) sB(0, 1, kb3);
        BARRIER();
        RB(bfB, 1, 1, 1); SB0();
        MC(afB, bfA, 0);
        BARRIER();
        // ph8: cluster(t+1,k1,n23); stage Ak1(t+3); drain tile t+2
        if (!last) {
            sA(1, 1, kb3 + 32);
            if constexpr (M_REP == 8) VMW(12); else VMW(8);
        }
        BARRIER();
        if (!last) { RA(afA, 0, 0); RB(bfA, 0, 0, 0); }
        SB0();
        MC(afB, bfB, 1);
        BARRIER();
    }

    const int wmg = m0 + wr * (M_REP * 16);
    const int wcol = wc * 128;

    if constexpr (MODE == 0) {
        float* Cb = (float*)Cv + (long)bz * c_batch;
        #pragma unroll
        for (int n = 0; n < 8; ++n) {
            const int ng = n0 + wcol + n * 16 + fl;
            const float badd = bias ? bias[ng] : 0.0f;
            #pragma unroll
            for (int m = 0; m < M_REP; ++m) {
                const int mg = wmg + m * 16 + quad * 4;
                #pragma unroll
                for (int r = 0; r < 4; ++r)
                    Cb[(long)(mg + r) * ldc + ng] = acc[m][n][r] + badd;
            }
        }
    } else {
        // modes 1/2: LDS-restage the BM x 256 bf16 tile, coalesced readout.
        unsigned short* Cb = (unsigned short*)Cv + (long)bz * c_batch;
        if constexpr (MODE == 2) {
            float* Db = Dsum + (long)bz * NN;
            #pragma unroll
            for (int m = 0; m < M_REP; ++m)
                #pragma unroll
                for (int n = 0; n < 8; ++n)
                    #pragma unroll
                    for (int r = 0; r < 4; ++r)
                        acc[m][n][r] = fexp2(acc[m][n][r]);
            #pragma unroll
            for (int n = 0; n < 8; ++n) {
                float csum = 0.f;
                #pragma unroll
                for (int m = 0; m < M_REP; ++m)
                    csum += acc[m][n][0] + acc[m][n][1] + acc[m][n][2] + acc[m][n][3];
                csum += __shfl_xor(csum, 16);
                csum += __shfl_xor(csum, 32);
                if (quad == 0) atomicAdd(&Db[n0 + wcol + n * 16 + fl], csum);
            }
        }
        // write phase: OUT[row][col ^ (quad<<4)]  (row>>2 & 3 == quad)
        #pragma unroll
        for (int m = 0; m < M_REP; ++m) {
            const int rowb = wr * (M_REP * 16) + m * 16 + quad * 4;
            #pragma unroll
            for (int n = 0; n < 8; ++n) {
                const int pc = (wcol + n * 16 + fl) ^ (quad << 4);
                #pragma unroll
                for (int r = 0; r < 4; ++r)
                    SH[(rowb + r) * 256 + pc] = f2bf(acc[m][n][r]);
            }
        }
        __syncthreads();
        // coalesced readout: short8 per thread, dwordx4 store
        #pragma unroll
        for (int k = 0; k < BM / 8; ++k) {
            const int idx = k * 256 + tid;
            const int row = idx >> 5, c8 = (idx & 31) * 8;
            const int lcol = c8 ^ (((row >> 2) & 3) << 4);
            short8 vv = *(const short8*)&SH[row * 256 + lcol];
            *(short8*)&Cb[(long)(m0 + row) * ldc + n0 + c8] = vv;
        }
    }
}

// fused fp32->bf16 convert for x, w_one (scaled by log2e), w_two
__global__ __launch_bounds__(256) void convert_all(
    const float* __restrict__ x, const float* __restrict__ w1, const float* __restrict__ w2,
    unsigned short* __restrict__ xb, unsigned short* __restrict__ w1b, unsigned short* __restrict__ w2b)
{
    const long NX = (long)BB * NN * FF / 8;
    const long NW = (long)FF * FF / 8;
    long t = (long)blockIdx.x * 256 + threadIdx.x;
    const float* in; unsigned short* out; float sc = 1.0f;
    if (t < NX) { in = x; out = xb; }
    else if (t < NX + NW) { in = w1; out = w1b; t -= NX; sc = LOG2E; }
    else if (t < NX + 2 * NW) { in = w2; out = w2b; t -= NX + NW; }
    else return;
    const long i = t * 8;
    float4 a = *(const float4*)(in + i);
    float4 b = *(const float4*)(in + i + 4);
    union { bf16x2 h[4]; short8 s8; } u;
    float2v v;
    v.x = a.x * sc; v.y = a.y * sc; u.h[0] = __builtin_convertvector(v, bf16x2);
    v.x = a.z * sc; v.y = a.w * sc; u.h[1] = __builtin_convertvector(v, bf16x2);
    v.x = b.x * sc; v.y = b.y * sc; u.h[2] = __builtin_convertvector(v, bf16x2);
    v.x = b.z * sc; v.y = b.w * sc; u.h[3] = __builtin_convertvector(v, bf16x2);
    *(short8*)(out + i) = u.s8;
}

// out[o,f] = bf16(in[f,o]) for dim x dim fp32 (dim % 32 == 0)
__global__ __launch_bounds__(256) void transpose_convert(
    const float* __restrict__ in, unsigned short* __restrict__ out, int dim)
{
    __shared__ float t[32][33];
    const int tx = threadIdx.x & 31, ty = threadIdx.x >> 5;
    const int x0 = blockIdx.x * 32, y0 = blockIdx.y * 32;
    #pragma unroll
    for (int k = 0; k < 32; k += 8)
        t[ty + k][tx] = in[(long)(y0 + ty + k) * dim + x0 + tx];
    __syncthreads();
    #pragma unroll
    for (int k = 0; k < 32; k += 8)
        out[(long)(x0 + ty + k) * dim + y0 + tx] = f2bf(t[tx][ty + k]);
}

__global__ __launch_bounds__(256) void zero_f32(float* __restrict__ p, long n)
{
    long i = (long)blockIdx.x * 256 + threadIdx.x;
    if (i < n) p[i] = 0.0f;
}

// supT[o,m] = bf16( sup[m,o] / D[m] ); sup[m,o] = Call[m*1536 + 1024 + o] (bf16).
__global__ __launch_bounds__(256) void scale_transpose(
    const unsigned short* __restrict__ Call, const float* __restrict__ D,
    unsigned short* __restrict__ supT, int batch0)
{
    __shared__ float t[32][33];
    __shared__ float rD[32];
    const int tx = threadIdx.x & 31, ty = threadIdx.x >> 5;
    const int mt = blockIdx.x * 32, ot = blockIdx.y * 32;
    const int b = batch0 + blockIdx.z;
    const unsigned short* Cb = Call + (long)b * NN * 1536;
    unsigned short* Tb = supT + (long)b * NN * FF;
    if (threadIdx.x < 32) rD[threadIdx.x] = 1.0f / D[(long)b * NN + mt + threadIdx.x];
    __syncthreads();
    #pragma unroll
    for (int k = 0; k < 32; k += 8) {
        unsigned short u = Cb[(long)(mt + ty + k) * 1536 + 1024 + ot + tx];
        union { unsigned uu; float f; } cv; cv.uu = ((unsigned)u) << 16;
        t[ty + k][tx] = cv.f;
    }
    __syncthreads();
    #pragma unroll
    for (int k = 0; k < 32; k += 8)
        Tb[(long)(ot + ty + k) * NN + mt + tx] = f2bf(t[tx][ty + k] * rD[tx]);
}

extern "C" void kernel_launch(void* const* d_in, const int* in_sizes, int n_in,
                              void* d_out, int out_size, void* d_ws, size_t ws_size,
                              hipStream_t stream)
{
    const float* x      = (const float*)d_in[0];
    const float* weight = (const float*)d_in[1];
    const float* bias   = (const float*)d_in[2];
    const float* w_one  = (const float*)d_in[3];
    const float* w_two  = (const float*)d_in[4];
    float* out = (float*)d_out;

    const long NF  = (long)NN * FF;      // 1,048,576
    const long NN2 = (long)NN * NN;      // 4,194,304
    const long CROW = 1536;              // C_all row stride (p1|p2|sup)

    // workspace carve
    char* p = (char*)d_ws;
    unsigned short* xb    = (unsigned short*)p; p += (size_t)BB * NF * 2;          // 16 MB
    unsigned short* Wall  = (unsigned short*)p; p += (size_t)CROW * FF * 2;        // 1.5 MB
    unsigned short* Call  = (unsigned short*)p; p += (size_t)BB * NN * CROW * 2;   // 48 MB
    unsigned short* supT  = (unsigned short*)p; p += (size_t)BB * NF * 2;          // 16 MB
    float*          Dsum  = (float*)p;          p += (size_t)BB * NN * 4;          // 64 KB
    unsigned short* E     = (unsigned short*)p;                                    // 64 MB (full) or 8 MB (batch)
    unsigned short* w1b = Wall;
    unsigned short* w2b = Wall + (size_t)FF * FF;
    unsigned short* wTb = Wall + (size_t)2 * FF * FF;

    const size_t fixed = (size_t)(p - (char*)d_ws);
    const bool full = ws_size >= fixed + (size_t)BB * NN2 * 2;

    dim3 blk(256);

    // 1) converts (w1 pre-scaled by log2e)
    convert_all<<<dim3(4352), blk, 0, stream>>>(x, w_one, w_two, xb, w1b, w2b);
    transpose_convert<<<dim3(FF / 32, FF / 32), blk, 0, stream>>>(weight, wTb, FF);
    zero_f32<<<dim3((BB * NN) / 256), blk, 0, stream>>>(Dsum, BB * NN);

    // 2) Call[n, e] = x[n,:]·Wall[e,:]  — 128x256 tile, (6,16,8) = 768 blocks
    gemm8p<4, 1><<<dim3(CROW / 256, NN / 128, BB), blk, 0, stream>>>(
        xb, Wall, Call, nullptr, nullptr, FF,
        FF, FF, (int)CROW, NF, 0, NN * CROW);

    if (full) {
        // 3) E[n,m] = exp2(p1·log2e dot p2); Dsum[b,m] += colsums.
        //    256x256 tile: (8,8,8) = 512 blocks
        gemm8p<8, 2><<<dim3(NN / 256, NN / 256, BB), blk, 0, stream>>>(
            Call, Call + FF, E, nullptr, Dsum, FF,
            (int)CROW, (int)CROW, NN, NN * CROW, NN * CROW, NN2);
        // 4) supT[o,m] = sup[m,o]/D[m]
        scale_transpose<<<dim3(NN / 32, FF / 32, BB), blk, 0, stream>>>(Call, Dsum, supT, 0);
        // 5) out[n,o] = E[n,:]·supT[o,:] + bias[o] — 128x256 tile, (2,16,8) = 256 blocks
        gemm8p<4, 0><<<dim3(FF / 256, NN / 128, BB), blk, 0, stream>>>(
            E, supT, out, bias, nullptr, NN,
            NN, NN, FF, NN2, NF, NF);
    } else {
        for (int b = 0; b < BB; ++b) {
            const unsigned short* Cb = Call + (size_t)b * NN * CROW;
            gemm8p<8, 2><<<dim3(NN / 256, NN / 256, 1), blk, 0, stream>>>(
                Cb, Cb + FF, E, nullptr, Dsum + (size_t)b * NN, FF,
                (int)CROW, (int)CROW, NN, 0, 0, 0);
            scale_transpose<<<dim3(NN / 32, FF / 32, 1), blk, 0, stream>>>(Call, Dsum, supT, b);
            gemm8p<4, 0><<<dim3(FF / 256, NN / 128, 1), blk, 0, stream>>>(
                E, supT + (size_t)b * NF, out + (size_t)b * NF, bias, nullptr, NN,
                NN, NN, FF, 0, 0, 0);
        }
    }
}

// Round 5
// 239.388 us; speedup vs baseline: 1.1320x; 1.0361x over previous
//
#include <hip/hip_runtime.h>
#include <math.h>

// B=8, N=2048, Fin=Fout=512, fp32 in/out. bf16 MFMA internally.
// out[n,o] = sum_m exp(adj[n,m]) * (sup[m,o] / D[m]),  D[m] = sum_n exp(adj[n,m])
// p1 is pre-scaled by log2(e) so adj accumulates in log2 domain -> raw v_exp_f32.
#define BB 8
#define NN 2048
#define FF 512
#define LOG2E 1.4426950408889634f

typedef __attribute__((ext_vector_type(8))) short short8;
typedef __attribute__((ext_vector_type(4))) float floatx4;
typedef __attribute__((ext_vector_type(2))) float float2v;
typedef __attribute__((ext_vector_type(2))) __bf16 bf16x2;

__device__ __forceinline__ unsigned short f2bf(float f) {
    union { float f; unsigned u; } v; v.f = f;
    unsigned r = v.u + 0x7FFFu + ((v.u >> 16) & 1u);
    return (unsigned short)(r >> 16);
}

__device__ __forceinline__ float fexp2(float x) {
#if __has_builtin(__builtin_amdgcn_exp2f)
    return __builtin_amdgcn_exp2f(x);
#else
    return __expf(x * 0.69314718056f);
#endif
}

#define SB0() __builtin_amdgcn_sched_barrier(0)
// RAW inline-asm barrier: opaque to the memory legalizer, so no implicit
// s_waitcnt vmcnt(0) drain gets attached (r4 A/B: this is the ONLY change).
#define BARRIER() do { SB0(); asm volatile("s_barrier" ::: "memory"); SB0(); } while (0)
#define GLDS(src, dst) __builtin_amdgcn_global_load_lds( \
    (const __attribute__((address_space(1))) void*)(src), \
    (__attribute__((address_space(3))) void*)(dst), 16, 0, 0)
#define VMW(n) asm volatile("s_waitcnt vmcnt(" #n ")" ::: "memory")

// ---------------------------------------------------------------------------
// 8-phase BT-GEMM with one-phase register read-ahead.
//   C[i,j] = sum_k A[i*a_ld+k] * B[j*b_ld+k]
// Tile BM x 256 (BM = M_REP*32), 256 thr = 4 waves (2M x 2N); per-wave output
// (M_REP*16) x 128, acc[M_REP][8]. BK=64 split in two 32-k halves; LDS holds
// 4 rotating slots per matrix [khalf][tile-parity].
// Phase p: [stage one half-tile][vmcnt@ph4/8][barrier][issue ds_reads for
// phase p+1 into the ALTERNATE reg set][sched0][MFMA cluster p][barrier].
// Reads drain under the previous cluster's MFMAs (read-ahead); counted
// vmcnt(2*LA+4) never drains to 0 mid-loop (T4); setprio around MFMA (T5).
// Schedule invariants hand-verified (see r2/r3 notes):
//  * publish: reads of a tile issue strictly after the ph4/ph8 vmcnt+barrier
//    that drains that tile's stages.
//  * overwrite: every stage S(q) issues after barrier B2(q-1); all reads of
//    the slot S(q) overwrites were lgkm-drained before their wave's B2(q-1).
//  * ph4 vmcnt leaves exactly {ph2,ph3,ph4} stages in flight -> tile t+1
//    fully resident before ph5; ph8 likewise for tile t+2.
// LDS swizzle (counter-verified 0 conflicts r2/r4): row r holds global 16B
// chunk c at slot c ^ ((r>>1)&3); reads use slot quad^((fl>>1)&3).
// Epilogue (modes 1/2): restage tile in LDS then coalesced short8 readout
// (r4: WRITE_SIZE 136->68 MB, confirmed).
// XCD swizzle: flat-bijective (nwg%8==0 for all grids) -> batch-per-XCD
// (r4: FETCH 74->25 MB, confirmed).
// modes: 0 = fp32 out + bias[j]; 1 = bf16 out; 2 = bf16 exp2(out) + Dsum.
// Requires K % 128 == 0, K >= 256.
// ---------------------------------------------------------------------------
template<int M_REP, int MODE>
__global__ __launch_bounds__(256, 1) void gemm8p(
    const unsigned short* __restrict__ A, const unsigned short* __restrict__ B,
    void* __restrict__ Cv, const float* __restrict__ bias, float* __restrict__ Dsum,
    int K, int a_ld, int b_ld, int ldc,
    long a_batch, long b_batch, long c_batch)
{
    constexpr int BM    = M_REP * 32;
    constexpr int LA    = BM / 64;           // A-half global_load_lds issues
    constexpr int ASLOT = BM * 32;           // elems per A slot
    constexpr int BSLOT = 256 * 32;
    constexpr int BBASE = 4 * ASLOT;
    constexpr int TOT   = 4 * ASLOT + 4 * BSLOT;

    __shared__ __align__(16) unsigned short SH[TOT];

    const int tid  = threadIdx.x;
    const int wave = tid >> 6;
    const int lane = tid & 63;
    const int wr   = wave >> 1;              // 0..1 (M)
    const int wc   = wave & 1;               // 0..1 (N)
    const int fl   = lane & 15;
    const int quad = lane >> 4;

    // XCD-bijective block swizzle: batch -> one XCD (L2-resident panels)
    const int gx = gridDim.x, gy = gridDim.y;
    int flat = blockIdx.x + gx * (blockIdx.y + gy * blockIdx.z);
    const int cpx = (gx * gy * gridDim.z) >> 3;
    flat = (flat & 7) * cpx + (flat >> 3);
    const int bx = flat % gx;
    const int rest = flat / gx;
    const int by = rest % gy;
    const int bz = rest / gy;

    const int m0 = by * BM;
    const int n0 = bx * 256;

    const unsigned short* Aptr = A + (long)bz * a_batch + (long)m0 * a_ld;
    const unsigned short* Bptr = B + (long)bz * b_batch + (long)n0 * b_ld;

    // staging source offsets (inverse-swizzled), loop-invariant
    int offA[LA], offB[4];
    #pragma unroll
    for (int i = 0; i < LA; ++i) {
        const int cl = i * 256 + tid;
        const int r = cl >> 2, s = cl & 3;
        offA[i] = r * a_ld + (s ^ ((r >> 1) & 3)) * 8;
    }
    #pragma unroll
    for (int i = 0; i < 4; ++i) {
        const int cl = i * 256 + tid;
        const int r = cl >> 2, s = cl & 3;
        offB[i] = r * b_ld + (s ^ ((r >> 1) & 3)) * 8;
    }

    // fragment ds_read bases (elems): row = base+fl, chunk = quad^((fl>>1)&3)
    const int swz = (quad ^ ((fl >> 1) & 3)) * 8;
    const int aRd = (wr * (M_REP * 16) + fl) * 32 + swz;
    const int bRd = (wc * 128 + fl) * 32 + swz;

    auto sA = [&](int kh, int db, int kb) {
        #pragma unroll
        for (int i = 0; i < LA; ++i)
            GLDS(Aptr + kb + offA[i], &SH[(kh * 2 + db) * ASLOT + (i * 256 + tid) * 8]);
    };
    auto sB = [&](int kh, int db, int kb) {
        #pragma unroll
        for (int i = 0; i < 4; ++i)
            GLDS(Bptr + kb + offB[i], &SH[BBASE + (kh * 2 + db) * BSLOT + (i * 256 + tid) * 8]);
    };

    floatx4 acc[M_REP][8] = {};
    short8 afA[M_REP], afB[M_REP], bfA[4], bfB[4];

    auto RA = [&](short8* af, int kh, int db) {
        const unsigned short* b = &SH[(kh * 2 + db) * ASLOT + aRd];
        #pragma unroll
        for (int m = 0; m < M_REP; ++m) af[m] = *(const short8*)(b + m * 512);
    };
    auto RB = [&](short8* bf, int kh, int db, int nh) {
        const unsigned short* b = &SH[BBASE + (kh * 2 + db) * BSLOT + bRd + nh * 2048];
        #pragma unroll
        for (int j = 0; j < 4; ++j) bf[j] = *(const short8*)(b + j * 512);
    };
    auto MC = [&](short8* af, short8* bf, int nh) {
        __builtin_amdgcn_s_setprio(1);
        #pragma unroll
        for (int m = 0; m < M_REP; ++m)
            #pragma unroll
            for (int j = 0; j < 4; ++j)
                acc[m][nh * 4 + j] = __builtin_amdgcn_mfma_f32_16x16x32_bf16(af[m], bf[j], acc[m][nh * 4 + j], 0, 0, 0);
        __builtin_amdgcn_s_setprio(0);
    };

    const int nt = K >> 6;
    const int ni = nt >> 1;

    // prologue: tiles 0,1 minus Bk1(1); drain tile 0, leave 3 halves in flight
    sA(0, 0, 0);  sB(0, 0, 0);  sA(1, 0, 32); sB(1, 0, 32);
    sA(0, 1, 64); sB(0, 1, 64); sA(1, 1, 96);
    if constexpr (M_REP == 8) VMW(12); else VMW(8);
    BARRIER();
    RA(afA, 0, 0); RB(bfA, 0, 0, 0);
    SB0();

    for (int i = 0; i < ni; ++i) {
        const bool last = (i == ni - 1);
        const int kb1 = (2 * i + 1) * 64, kb2 = kb1 + 64, kb3 = kb2 + 64;

        // ph1: cluster(t,k0,n01); stage Bk1(t+1)
        sB(1, 1, kb1 + 32);
        BARRIER();
        RB(bfB, 0, 0, 1); SB0();
        MC(afA, bfA, 0);
        BARRIER();
        // ph2: cluster(t,k0,n23); stage Ak0(t+2)
        if (!last) sA(0, 0, kb2);
        BARRIER();
        RA(afB, 1, 0); RB(bfA, 1, 0, 0); SB0();
        MC(afA, bfB, 1);
        BARRIER();
        // ph3: cluster(t,k1,n01); stage Bk0(t+2)
        if (!last) sB(0, 0, kb2);
        BARRIER();
        RB(bfB, 1, 0, 1); SB0();
        MC(afB, bfA, 0);
        BARRIER();
        // ph4: cluster(t,k1,n23); stage Ak1(t+2); drain tile t+1
        if (!last) {
            sA(1, 0, kb2 + 32);
            if constexpr (M_REP == 8) VMW(12); else VMW(8);
        } else {
            VMW(0);
        }
        BARRIER();
        RA(afA, 0, 1); RB(bfA, 0, 1, 0); SB0();
        MC(afB, bfB, 1);
        BARRIER();
        // ph5: cluster(t+1,k0,n01); stage Bk1(t+2)
        if (!last) sB(1, 0, kb2 + 32);
        BARRIER();
        RB(bfB, 0, 1, 1); SB0();
        MC(afA, bfA, 0);
        BARRIER();
        // ph6: cluster(t+1,k0,n23); stage Ak0(t+3)
        if (!last) sA(0, 1, kb3);
        BARRIER();
        RA(afB, 1, 1); RB(bfA, 1, 1, 0); SB0();
        MC(afA, bfB, 1);
        BARRIER();
        // ph7: cluster(t+1,k1,n01); stage Bk0(t+3)
        if (!last) sB(0, 1, kb3);
        BARRIER();
        RB(bfB, 1, 1, 1); SB0();
        MC(afB, bfA, 0);
        BARRIER();
        // ph8: cluster(t+1,k1,n23); stage Ak1(t+3); drain tile t+2
        if (!last) {
            sA(1, 1, kb3 + 32);
            if constexpr (M_REP == 8) VMW(12); else VMW(8);
        }
        BARRIER();
        if (!last) { RA(afA, 0, 0); RB(bfA, 0, 0, 0); }
        SB0();
        MC(afB, bfB, 1);
        BARRIER();
    }

    const int wmg = m0 + wr * (M_REP * 16);
    const int wcol = wc * 128;

    if constexpr (MODE == 0) {
        float* Cb = (float*)Cv + (long)bz * c_batch;
        #pragma unroll
        for (int n = 0; n < 8; ++n) {
            const int ng = n0 + wcol + n * 16 + fl;
            const float badd = bias ? bias[ng] : 0.0f;
            #pragma unroll
            for (int m = 0; m < M_REP; ++m) {
                const int mg = wmg + m * 16 + quad * 4;
                #pragma unroll
                for (int r = 0; r < 4; ++r)
                    Cb[(long)(mg + r) * ldc + ng] = acc[m][n][r] + badd;
            }
        }
    } else {
        // modes 1/2: LDS-restage the BM x 256 bf16 tile, coalesced readout.
        unsigned short* Cb = (unsigned short*)Cv + (long)bz * c_batch;
        if constexpr (MODE == 2) {
            float* Db = Dsum + (long)bz * NN;
            #pragma unroll
            for (int m = 0; m < M_REP; ++m)
                #pragma unroll
                for (int n = 0; n < 8; ++n)
                    #pragma unroll
                    for (int r = 0; r < 4; ++r)
                        acc[m][n][r] = fexp2(acc[m][n][r]);
            #pragma unroll
            for (int n = 0; n < 8; ++n) {
                float csum = 0.f;
                #pragma unroll
                for (int m = 0; m < M_REP; ++m)
                    csum += acc[m][n][0] + acc[m][n][1] + acc[m][n][2] + acc[m][n][3];
                csum += __shfl_xor(csum, 16);
                csum += __shfl_xor(csum, 32);
                if (quad == 0) atomicAdd(&Db[n0 + wcol + n * 16 + fl], csum);
            }
        }
        __syncthreads();
        // write phase: OUT[row][col ^ (quad<<4)]  (row>>2 & 3 == quad)
        #pragma unroll
        for (int m = 0; m < M_REP; ++m) {
            const int rowb = wr * (M_REP * 16) + m * 16 + quad * 4;
            #pragma unroll
            for (int n = 0; n < 8; ++n) {
                const int pc = (wcol + n * 16 + fl) ^ (quad << 4);
                #pragma unroll
                for (int r = 0; r < 4; ++r)
                    SH[(rowb + r) * 256 + pc] = f2bf(acc[m][n][r]);
            }
        }
        __syncthreads();
        // coalesced readout: short8 per thread, dwordx4 store
        #pragma unroll
        for (int k = 0; k < BM / 8; ++k) {
            const int idx = k * 256 + tid;
            const int row = idx >> 5, c8 = (idx & 31) * 8;
            const int lcol = c8 ^ (((row >> 2) & 3) << 4);
            short8 vv = *(const short8*)&SH[row * 256 + lcol];
            *(short8*)&Cb[(long)(m0 + row) * ldc + n0 + c8] = vv;
        }
    }
}

// fused fp32->bf16 convert for x, w_one (scaled by log2e), w_two
__global__ __launch_bounds__(256) void convert_all(
    const float* __restrict__ x, const float* __restrict__ w1, const float* __restrict__ w2,
    unsigned short* __restrict__ xb, unsigned short* __restrict__ w1b, unsigned short* __restrict__ w2b)
{
    const long NX = (long)BB * NN * FF / 8;
    const long NW = (long)FF * FF / 8;
    long t = (long)blockIdx.x * 256 + threadIdx.x;
    const float* in; unsigned short* out; float sc = 1.0f;
    if (t < NX) { in = x; out = xb; }
    else if (t < NX + NW) { in = w1; out = w1b; t -= NX; sc = LOG2E; }
    else if (t < NX + 2 * NW) { in = w2; out = w2b; t -= NX + NW; }
    else return;
    const long i = t * 8;
    float4 a = *(const float4*)(in + i);
    float4 b = *(const float4*)(in + i + 4);
    union { bf16x2 h[4]; short8 s8; } u;
    float2v v;
    v.x = a.x * sc; v.y = a.y * sc; u.h[0] = __builtin_convertvector(v, bf16x2);
    v.x = a.z * sc; v.y = a.w * sc; u.h[1] = __builtin_convertvector(v, bf16x2);
    v.x = b.x * sc; v.y = b.y * sc; u.h[2] = __builtin_convertvector(v, bf16x2);
    v.x = b.z * sc; v.y = b.w * sc; u.h[3] = __builtin_convertvector(v, bf16x2);
    *(short8*)(out + i) = u.s8;
}

// out[o,f] = bf16(in[f,o]) for dim x dim fp32 (dim % 32 == 0)
__global__ __launch_bounds__(256) void transpose_convert(
    const float* __restrict__ in, unsigned short* __restrict__ out, int dim)
{
    __shared__ float t[32][33];
    const int tx = threadIdx.x & 31, ty = threadIdx.x >> 5;
    const int x0 = blockIdx.x * 32, y0 = blockIdx.y * 32;
    #pragma unroll
    for (int k = 0; k < 32; k += 8)
        t[ty + k][tx] = in[(long)(y0 + ty + k) * dim + x0 + tx];
    __syncthreads();
    #pragma unroll
    for (int k = 0; k < 32; k += 8)
        out[(long)(x0 + ty + k) * dim + y0 + tx] = f2bf(t[tx][ty + k]);
}

__global__ __launch_bounds__(256) void zero_f32(float* __restrict__ p, long n)
{
    long i = (long)blockIdx.x * 256 + threadIdx.x;
    if (i < n) p[i] = 0.0f;
}

// supT[o,m] = bf16( sup[m,o] / D[m] ); sup[m,o] = Call[m*1536 + 1024 + o] (bf16).
__global__ __launch_bounds__(256) void scale_transpose(
    const unsigned short* __restrict__ Call, const float* __restrict__ D,
    unsigned short* __restrict__ supT, int batch0)
{
    __shared__ float t[32][33];
    __shared__ float rD[32];
    const int tx = threadIdx.x & 31, ty = threadIdx.x >> 5;
    const int mt = blockIdx.x * 32, ot = blockIdx.y * 32;
    const int b = batch0 + blockIdx.z;
    const unsigned short* Cb = Call + (long)b * NN * 1536;
    unsigned short* Tb = supT + (long)b * NN * FF;
    if (threadIdx.x < 32) rD[threadIdx.x] = 1.0f / D[(long)b * NN + mt + threadIdx.x];
    __syncthreads();
    #pragma unroll
    for (int k = 0; k < 32; k += 8) {
        unsigned short u = Cb[(long)(mt + ty + k) * 1536 + 1024 + ot + tx];
        union { unsigned uu; float f; } cv; cv.uu = ((unsigned)u) << 16;
        t[ty + k][tx] = cv.f;
    }
    __syncthreads();
    #pragma unroll
    for (int k = 0; k < 32; k += 8)
        Tb[(long)(ot + ty + k) * NN + mt + tx] = f2bf(t[tx][ty + k] * rD[tx]);
}

extern "C" void kernel_launch(void* const* d_in, const int* in_sizes, int n_in,
                              void* d_out, int out_size, void* d_ws, size_t ws_size,
                              hipStream_t stream)
{
    const float* x      = (const float*)d_in[0];
    const float* weight = (const float*)d_in[1];
    const float* bias   = (const float*)d_in[2];
    const float* w_one  = (const float*)d_in[3];
    const float* w_two  = (const float*)d_in[4];
    float* out = (float*)d_out;

    const long NF  = (long)NN * FF;      // 1,048,576
    const long NN2 = (long)NN * NN;      // 4,194,304
    const long CROW = 1536;              // C_all row stride (p1|p2|sup)

    // workspace carve
    char* p = (char*)d_ws;
    unsigned short* xb    = (unsigned short*)p; p += (size_t)BB * NF * 2;          // 16 MB
    unsigned short* Wall  = (unsigned short*)p; p += (size_t)CROW * FF * 2;        // 1.5 MB
    unsigned short* Call  = (unsigned short*)p; p += (size_t)BB * NN * CROW * 2;   // 48 MB
    unsigned short* supT  = (unsigned short*)p; p += (size_t)BB * NF * 2;          // 16 MB
    float*          Dsum  = (float*)p;          p += (size_t)BB * NN * 4;          // 64 KB
    unsigned short* E     = (unsigned short*)p;                                    // 64 MB (full) or 8 MB (batch)
    unsigned short* w1b = Wall;
    unsigned short* w2b = Wall + (size_t)FF * FF;
    unsigned short* wTb = Wall + (size_t)2 * FF * FF;

    const size_t fixed = (size_t)(p - (char*)d_ws);
    const bool full = ws_size >= fixed + (size_t)BB * NN2 * 2;

    dim3 blk(256);

    // 1) converts (w1 pre-scaled by log2e)
    convert_all<<<dim3(4352), blk, 0, stream>>>(x, w_one, w_two, xb, w1b, w2b);
    transpose_convert<<<dim3(FF / 32, FF / 32), blk, 0, stream>>>(weight, wTb, FF);
    zero_f32<<<dim3((BB * NN) / 256), blk, 0, stream>>>(Dsum, BB * NN);

    // 2) Call[n, e] = x[n,:]·Wall[e,:]  — 128x256 tile, (6,16,8) = 768 blocks
    gemm8p<4, 1><<<dim3(CROW / 256, NN / 128, BB), blk, 0, stream>>>(
        xb, Wall, Call, nullptr, nullptr, FF,
        FF, FF, (int)CROW, NF, 0, NN * CROW);

    if (full) {
        // 3) E[n,m] = exp2(p1·log2e dot p2); Dsum[b,m] += colsums.
        //    256x256 tile: (8,8,8) = 512 blocks
        gemm8p<8, 2><<<dim3(NN / 256, NN / 256, BB), blk, 0, stream>>>(
            Call, Call + FF, E, nullptr, Dsum, FF,
            (int)CROW, (int)CROW, NN, NN * CROW, NN * CROW, NN2);
        // 4) supT[o,m] = sup[m,o]/D[m]
        scale_transpose<<<dim3(NN / 32, FF / 32, BB), blk, 0, stream>>>(Call, Dsum, supT, 0);
        // 5) out[n,o] = E[n,:]·supT[o,:] + bias[o] — 128x256 tile, (2,16,8) = 256 blocks
        gemm8p<4, 0><<<dim3(FF / 256, NN / 128, BB), blk, 0, stream>>>(
            E, supT, out, bias, nullptr, NN,
            NN, NN, FF, NN2, NF, NF);
    } else {
        for (int b = 0; b < BB; ++b) {
            const unsigned short* Cb = Call + (size_t)b * NN * CROW;
            gemm8p<8, 2><<<dim3(NN / 256, NN / 256, 1), blk, 0, stream>>>(
                Cb, Cb + FF, E, nullptr, Dsum + (size_t)b * NN, FF,
                (int)CROW, (int)CROW, NN, 0, 0, 0);
            scale_transpose<<<dim3(NN / 32, FF / 32, 1), blk, 0, stream>>>(Call, Dsum, supT, b);
            gemm8p<4, 0><<<dim3(FF / 256, NN / 128, 1), blk, 0, stream>>>(
                E, supT + (size_t)b * NF, out + (size_t)b * NF, bias, nullptr, NN,
                NN, NN, FF, 0, 0, 0);
        }
    }
}

// Round 6
// 234.993 us; speedup vs baseline: 1.1532x; 1.0187x over previous
//
#include <hip/hip_runtime.h>
#include <math.h>

// B=8, N=2048, Fin=Fout=512, fp32 in/out. bf16 MFMA internally.
// out[n,o] = sum_m exp(adj[n,m]) * (sup[m,o] / D[m]),  D[m] = sum_n exp(adj[n,m])
// p1 is pre-scaled by log2(e) so adj accumulates in log2 domain -> raw v_exp_f32.
#define BB 8
#define NN 2048
#define FF 512
#define LOG2E 1.4426950408889634f

typedef __attribute__((ext_vector_type(8))) short short8;
typedef __attribute__((ext_vector_type(4))) float floatx4;
typedef __attribute__((ext_vector_type(2))) float float2v;
typedef __attribute__((ext_vector_type(2))) __bf16 bf16x2;

__device__ __forceinline__ unsigned short f2bf(float f) {
    union { float f; unsigned u; } v; v.f = f;
    unsigned r = v.u + 0x7FFFu + ((v.u >> 16) & 1u);
    return (unsigned short)(r >> 16);
}

__device__ __forceinline__ float fexp2(float x) {
#if __has_builtin(__builtin_amdgcn_exp2f)
    return __builtin_amdgcn_exp2f(x);
#else
    return __expf(x * 0.69314718056f);
#endif
}

__device__ __forceinline__ void pk_store(unsigned short* p0, unsigned short* p1,
                                         float a, float b) {
    union { bf16x2 h; unsigned short s[2]; } u;
    float2v v; v.x = a; v.y = b;
    u.h = __builtin_convertvector(v, bf16x2);
    *p0 = u.s[0]; *p1 = u.s[1];
}

#define BAR() __builtin_amdgcn_s_barrier()
// rule #18: single sched fence after the lgkm wait; NO other sched pins
// (m141: blanket sched_barrier(0) pinning -> 510 TF, exactly the r2-r5 plateau)
#define LGKM0() do { asm volatile("s_waitcnt lgkmcnt(0)" ::: "memory"); \
                     __builtin_amdgcn_sched_barrier(0); } while (0)
#define GLDS(src, dst) __builtin_amdgcn_global_load_lds( \
    (const __attribute__((address_space(1))) void*)(src), \
    (__attribute__((address_space(3))) void*)(dst), 16, 0, 0)
#define VMW(n) asm volatile("s_waitcnt vmcnt(" #n ")" ::: "memory")

// ---------------------------------------------------------------------------
// m201-faithful 8-phase BT-GEMM: C[i,j] = sum_k A[i*a_ld+k] * B[j*b_ld+k]
// 256x256 tile, 512 thr = 8 waves (2M x 4N, 2 waves/SIMD); wave tile 128x64,
// acc[8][4] 16x16 frags. BK=64 in two 32-k halves; 4 rotating LDS slots per
// matrix [khalf][tile-parity], 128 KB total.
// Phase p: { ds_read p's subtile | stage ONE half | vmcnt(6)@ph4/8 only |
//            s_barrier | lgkmcnt(0)+sched0 | setprio(1) 16xMFMA setprio(0) |
//            s_barrier }
// Reads issue BEFORE the begin-barrier (overlap straggler wait, m201 pattern);
// compiler is otherwise free to schedule (no order-pinning).
// Ledger (hand-verified, reads-early layout):
//  publish: every slot read at phase p was vmcnt-drained at a ph4/ph8 barrier
//   strictly before p (Ak0(t)/Bk0(t)/Ak1(t)/Bk1(t): staged prev ph2/3/4/5,
//   drained prev-ph8; Ak0/Bk0(t+1): staged prev ph6/7, drained this ph4;
//   Bk1(t+1): staged this ph1, drained this ph4, read ph7).
//  overwrite: every stage at phase q targets a slot whose reads completed
//   before B2(q-1) (reads complete at lgkm0 right after B1 of their phase).
//  vmcnt ledger (loads/thread, 2 per stage): prologue 14 issued, VMW(6)
//   drains tile0's 8; ph4: 14 outstanding -> 6 = {ph2,ph3,ph4}; ph8:
//   14 -> 6 = {ph6,ph7,ph8}. Last iter: ph4 VMW(0) (only ph1's 2 out).
// LDS chunk-XOR swizzle (counter-verified 0 conflicts r2/r4/r5): row r holds
// global 16B chunk c at slot c ^ ((r>>1)&3); reads use quad ^ ((fl>>1)&3);
// staging sources pre-apply the involution (m173).
// Epilogue: modes 1/2 LDS-restage + coalesced short8 readout (r4: WRITE
// 136->68 MB confirmed). XCD flat-bijective swizzle (r4: FETCH 74->25 MB).
// modes: 0 = fp32 out + bias[j]; 1 = bf16 out; 2 = bf16 exp2(out) + Dsum.
// Requires K % 128 == 0, K >= 256.
// ---------------------------------------------------------------------------
template<int MODE>
__global__ __launch_bounds__(512) void gemm256(
    const unsigned short* __restrict__ A, const unsigned short* __restrict__ B,
    void* __restrict__ Cv, const float* __restrict__ bias, float* __restrict__ Dsum,
    int K, int a_ld, int b_ld, int ldc,
    long a_batch, long b_batch, long c_batch)
{
    constexpr int SLOT = 256 * 32;           // elems per half-tile slot
    __shared__ __align__(16) unsigned short SH[8 * SLOT];   // A:0-3, B:4-7

    const int tid  = threadIdx.x;
    const int wave = tid >> 6;
    const int lane = tid & 63;
    const int wr   = wave >> 2;              // 0..1 (M)
    const int wc   = wave & 3;               // 0..3 (N)
    const int fl   = lane & 15;
    const int quad = lane >> 4;

    // XCD-bijective block swizzle (all grids %8==0)
    const int gx = gridDim.x, gy = gridDim.y;
    int flat = blockIdx.x + gx * (blockIdx.y + gy * blockIdx.z);
    const int cpx = (gx * gy * gridDim.z) >> 3;
    flat = (flat & 7) * cpx + (flat >> 3);
    const int bx = flat % gx;
    const int rest = flat / gx;
    const int by = rest % gy;
    const int bz = rest / gy;

    const int m0 = by * 256;
    const int n0 = bx * 256;

    const unsigned short* Aptr = A + (long)bz * a_batch + (long)m0 * a_ld;
    const unsigned short* Bptr = B + (long)bz * b_batch + (long)n0 * b_ld;

    // staging source offsets (inverse-swizzled), 2 chunks per thread per half
    int offA[2], offB[2];
    #pragma unroll
    for (int i = 0; i < 2; ++i) {
        const int cl = i * 512 + tid;
        const int r = cl >> 2, s = cl & 3;
        const int c = s ^ ((r >> 1) & 3);
        offA[i] = r * a_ld + c * 8;
        offB[i] = r * b_ld + c * 8;
    }

    // fragment ds_read bases (elems): row = base+fl, chunk = quad^((fl>>1)&3)
    const int swz = (quad ^ ((fl >> 1) & 3)) * 8;
    const int aRd = (wr * 128 + fl) * 32 + swz;
    const int bRd = (wc * 64 + fl) * 32 + swz;

    auto sA = [&](int kh, int db, int kb) {
        #pragma unroll
        for (int i = 0; i < 2; ++i)
            GLDS(Aptr + kb + offA[i], &SH[(kh * 2 + db) * SLOT + (i * 512 + tid) * 8]);
    };
    auto sB = [&](int kh, int db, int kb) {
        #pragma unroll
        for (int i = 0; i < 2; ++i)
            GLDS(Bptr + kb + offB[i], &SH[(4 + kh * 2 + db) * SLOT + (i * 512 + tid) * 8]);
    };

    floatx4 acc[8][4] = {};
    short8 af[8], bf[2];

    auto RA = [&](int kh, int db) {
        const unsigned short* b = &SH[(kh * 2 + db) * SLOT + aRd];
        #pragma unroll
        for (int m = 0; m < 8; ++m) af[m] = *(const short8*)(b + m * 512);
    };
    auto RB = [&](int kh, int db, int nh) {
        const unsigned short* b = &SH[(4 + kh * 2 + db) * SLOT + bRd + nh * 1024];
        bf[0] = *(const short8*)(b);
        bf[1] = *(const short8*)(b + 512);
    };
    auto MC = [&](int nh) {
        __builtin_amdgcn_s_setprio(1);
        #pragma unroll
        for (int m = 0; m < 8; ++m) {
            acc[m][nh * 2]     = __builtin_amdgcn_mfma_f32_16x16x32_bf16(af[m], bf[0], acc[m][nh * 2], 0, 0, 0);
            acc[m][nh * 2 + 1] = __builtin_amdgcn_mfma_f32_16x16x32_bf16(af[m], bf[1], acc[m][nh * 2 + 1], 0, 0, 0);
        }
        __builtin_amdgcn_s_setprio(0);
    };

    const int nt = K >> 6;
    const int ni = nt >> 1;

    // prologue: tiles 0,1 minus Bk1(1); drain tile 0 (8 loads), keep 6 in flight
    sA(0, 0, 0);  sB(0, 0, 0);  sA(1, 0, 32); sB(1, 0, 32);
    sA(0, 1, 64); sB(0, 1, 64); sA(1, 1, 96);
    VMW(6);
    BAR();

    for (int i = 0; i < ni; ++i) {
        const bool last = (i == ni - 1);
        const int kb1 = (2 * i + 1) * 64, kb2 = kb1 + 64, kb3 = kb2 + 64;

        // ph1: Q(t,k0,n01); stage Bk1(t+1)
        RA(0, 0); RB(0, 0, 0);
        sB(1, 1, kb1 + 32);
        BAR(); LGKM0(); MC(0); BAR();
        // ph2: Q(t,k0,n23); stage Ak0(t+2)
        RB(0, 0, 1);
        if (!last) sA(0, 0, kb2);
        BAR(); LGKM0(); MC(1); BAR();
        // ph3: Q(t,k1,n01); stage Bk0(t+2)
        RA(1, 0); RB(1, 0, 0);
        if (!last) sB(0, 0, kb2);
        BAR(); LGKM0(); MC(0); BAR();
        // ph4: Q(t,k1,n23); stage Ak1(t+2); drain through tile t+1 (+ph1 stage)
        RB(1, 0, 1);
        if (!last) { sA(1, 0, kb2 + 32); VMW(6); }
        else       { VMW(0); }
        BAR(); LGKM0(); MC(1); BAR();
        // ph5: Q(t+1,k0,n01); stage Bk1(t+2)
        RA(0, 1); RB(0, 1, 0);
        if (!last) sB(1, 0, kb2 + 32);
        BAR(); LGKM0(); MC(0); BAR();
        // ph6: Q(t+1,k0,n23); stage Ak0(t+3)
        RB(0, 1, 1);
        if (!last) sA(0, 1, kb3);
        BAR(); LGKM0(); MC(1); BAR();
        // ph7: Q(t+1,k1,n01); stage Bk0(t+3)
        RA(1, 1); RB(1, 1, 0);
        if (!last) sB(0, 1, kb3);
        BAR(); LGKM0(); MC(0); BAR();
        // ph8: Q(t+1,k1,n23); stage Ak1(t+3); drain through tile t+2
        RB(1, 1, 1);
        if (!last) { sA(1, 1, kb3 + 32); VMW(6); }
        BAR(); LGKM0(); MC(1); BAR();
    }

    const int wmg = m0 + wr * 128;
    const int wcol = wc * 64;

    if constexpr (MODE == 0) {
        float* Cb = (float*)Cv + (long)bz * c_batch;
        #pragma unroll
        for (int n = 0; n < 4; ++n) {
            const int ng = n0 + wcol + n * 16 + fl;
            const float badd = bias ? bias[ng] : 0.0f;
            #pragma unroll
            for (int m = 0; m < 8; ++m) {
                const int mg = wmg + m * 16 + quad * 4;
                #pragma unroll
                for (int r = 0; r < 4; ++r)
                    Cb[(long)(mg + r) * ldc + ng] = acc[m][n][r] + badd;
            }
        }
    } else {
        // modes 1/2: LDS-restage the 256x256 bf16 tile, coalesced readout.
        unsigned short* Cb = (unsigned short*)Cv + (long)bz * c_batch;
        if constexpr (MODE == 2) {
            float* Db = Dsum + (long)bz * NN;
            #pragma unroll
            for (int m = 0; m < 8; ++m)
                #pragma unroll
                for (int n = 0; n < 4; ++n)
                    #pragma unroll
                    for (int r = 0; r < 4; ++r)
                        acc[m][n][r] = fexp2(acc[m][n][r]);
            #pragma unroll
            for (int n = 0; n < 4; ++n) {
                float csum = 0.f;
                #pragma unroll
                for (int m = 0; m < 8; ++m)
                    csum += acc[m][n][0] + acc[m][n][1] + acc[m][n][2] + acc[m][n][3];
                csum += __shfl_xor(csum, 16);
                csum += __shfl_xor(csum, 32);
                if (quad == 0) atomicAdd(&Db[n0 + wcol + n * 16 + fl], csum);
            }
        }
        __syncthreads();
        // write: SH[row][col ^ (quad<<4)]  ((row>>2)&3 == quad)
        #pragma unroll
        for (int m = 0; m < 8; ++m) {
            const int rowb = wr * 128 + m * 16 + quad * 4;
            #pragma unroll
            for (int n = 0; n < 4; ++n) {
                const int pc = (wcol + n * 16 + fl) ^ (quad << 4);
                #pragma unroll
                for (int r = 0; r < 4; ++r)
                    SH[(rowb + r) * 256 + pc] = f2bf(acc[m][n][r]);
            }
        }
        __syncthreads();
        // coalesced readout: short8 per thread, dwordx4 store
        #pragma unroll
        for (int k = 0; k < 16; ++k) {
            const int idx = k * 512 + tid;
            const int row = idx >> 5, c8 = (idx & 31) * 8;
            const int lcol = c8 ^ (((row >> 2) & 3) << 4);
            short8 vv = *(const short8*)&SH[row * 256 + lcol];
            *(short8*)&Cb[(long)(m0 + row) * ldc + n0 + c8] = vv;
        }
    }
}

// fused fp32->bf16 convert for x, w_one (scaled by log2e), w_two
__global__ __launch_bounds__(256) void convert_all(
    const float* __restrict__ x, const float* __restrict__ w1, const float* __restrict__ w2,
    unsigned short* __restrict__ xb, unsigned short* __restrict__ w1b, unsigned short* __restrict__ w2b)
{
    const long NX = (long)BB * NN * FF / 8;
    const long NW = (long)FF * FF / 8;
    long t = (long)blockIdx.x * 256 + threadIdx.x;
    const float* in; unsigned short* out; float sc = 1.0f;
    if (t < NX) { in = x; out = xb; }
    else if (t < NX + NW) { in = w1; out = w1b; t -= NX; sc = LOG2E; }
    else if (t < NX + 2 * NW) { in = w2; out = w2b; t -= NX + NW; }
    else return;
    const long i = t * 8;
    float4 a = *(const float4*)(in + i);
    float4 b = *(const float4*)(in + i + 4);
    union { bf16x2 h[4]; short8 s8; } u;
    float2v v;
    v.x = a.x * sc; v.y = a.y * sc; u.h[0] = __builtin_convertvector(v, bf16x2);
    v.x = a.z * sc; v.y = a.w * sc; u.h[1] = __builtin_convertvector(v, bf16x2);
    v.x = b.x * sc; v.y = b.y * sc; u.h[2] = __builtin_convertvector(v, bf16x2);
    v.x = b.z * sc; v.y = b.w * sc; u.h[3] = __builtin_convertvector(v, bf16x2);
    *(short8*)(out + i) = u.s8;
}

// out[o,f] = bf16(in[f,o]) for dim x dim fp32 (dim % 32 == 0)
__global__ __launch_bounds__(256) void transpose_convert(
    const float* __restrict__ in, unsigned short* __restrict__ out, int dim)
{
    __shared__ float t[32][33];
    const int tx = threadIdx.x & 31, ty = threadIdx.x >> 5;
    const int x0 = blockIdx.x * 32, y0 = blockIdx.y * 32;
    #pragma unroll
    for (int k = 0; k < 32; k += 8)
        t[ty + k][tx] = in[(long)(y0 + ty + k) * dim + x0 + tx];
    __syncthreads();
    #pragma unroll
    for (int k = 0; k < 32; k += 8)
        out[(long)(x0 + ty + k) * dim + y0 + tx] = f2bf(t[tx][ty + k]);
}

__global__ __launch_bounds__(256) void zero_f32(float* __restrict__ p, long n)
{
    long i = (long)blockIdx.x * 256 + threadIdx.x;
    if (i < n) p[i] = 0.0f;
}

// supT[o,m] = bf16( sup[m,o] / D[m] ); sup[m,o] = Call[m*1536 + 1024 + o] (bf16).
__global__ __launch_bounds__(256) void scale_transpose(
    const unsigned short* __restrict__ Call, const float* __restrict__ D,
    unsigned short* __restrict__ supT, int batch0)
{
    __shared__ float t[32][33];
    __shared__ float rD[32];
    const int tx = threadIdx.x & 31, ty = threadIdx.x >> 5;
    const int mt = blockIdx.x * 32, ot = blockIdx.y * 32;
    const int b = batch0 + blockIdx.z;
    const unsigned short* Cb = Call + (long)b * NN * 1536;
    unsigned short* Tb = supT + (long)b * NN * FF;
    if (threadIdx.x < 32) rD[threadIdx.x] = 1.0f / D[(long)b * NN + mt + threadIdx.x];
    __syncthreads();
    #pragma unroll
    for (int k = 0; k < 32; k += 8) {
        unsigned short u = Cb[(long)(mt + ty + k) * 1536 + 1024 + ot + tx];
        union { unsigned uu; float f; } cv; cv.uu = ((unsigned)u) << 16;
        t[ty + k][tx] = cv.f;
    }
    __syncthreads();
    #pragma unroll
    for (int k = 0; k < 32; k += 8)
        Tb[(long)(ot + ty + k) * NN + mt + tx] = f2bf(t[tx][ty + k] * rD[tx]);
}

extern "C" void kernel_launch(void* const* d_in, const int* in_sizes, int n_in,
                              void* d_out, int out_size, void* d_ws, size_t ws_size,
                              hipStream_t stream)
{
    const float* x      = (const float*)d_in[0];
    const float* weight = (const float*)d_in[1];
    const float* bias   = (const float*)d_in[2];
    const float* w_one  = (const float*)d_in[3];
    const float* w_two  = (const float*)d_in[4];
    float* out = (float*)d_out;

    const long NF  = (long)NN * FF;      // 1,048,576
    const long NN2 = (long)NN * NN;      // 4,194,304
    const long CROW = 1536;              // C_all row stride (p1|p2|sup)

    // workspace carve
    char* p = (char*)d_ws;
    unsigned short* xb    = (unsigned short*)p; p += (size_t)BB * NF * 2;          // 16 MB
    unsigned short* Wall  = (unsigned short*)p; p += (size_t)CROW * FF * 2;        // 1.5 MB
    unsigned short* Call  = (unsigned short*)p; p += (size_t)BB * NN * CROW * 2;   // 48 MB
    unsigned short* supT  = (unsigned short*)p; p += (size_t)BB * NF * 2;          // 16 MB
    float*          Dsum  = (float*)p;          p += (size_t)BB * NN * 4;          // 64 KB
    unsigned short* E     = (unsigned short*)p;                                    // 64 MB (full) or 8 MB (batch)
    unsigned short* w1b = Wall;
    unsigned short* w2b = Wall + (size_t)FF * FF;
    unsigned short* wTb = Wall + (size_t)2 * FF * FF;

    const size_t fixed = (size_t)(p - (char*)d_ws);
    const bool full = ws_size >= fixed + (size_t)BB * NN2 * 2;

    dim3 blk(256), blk5(512);

    // 1) converts (w1 pre-scaled by log2e)
    convert_all<<<dim3(4352), blk, 0, stream>>>(x, w_one, w_two, xb, w1b, w2b);
    transpose_convert<<<dim3(FF / 32, FF / 32), blk, 0, stream>>>(weight, wTb, FF);
    zero_f32<<<dim3((BB * NN) / 256), blk, 0, stream>>>(Dsum, BB * NN);

    // 2) Call[n, e] = x[n,:]·Wall[e,:]  — 256x256, (6,8,8) = 384 blocks
    gemm256<1><<<dim3(CROW / 256, NN / 256, BB), blk5, 0, stream>>>(
        xb, Wall, Call, nullptr, nullptr, FF,
        FF, FF, (int)CROW, NF, 0, NN * CROW);

    if (full) {
        // 3) E[n,m] = exp2(p1·log2e dot p2); Dsum[b,m] += colsums.
        //    (8,8,8) = 512 blocks
        gemm256<2><<<dim3(NN / 256, NN / 256, BB), blk5, 0, stream>>>(
            Call, Call + FF, E, nullptr, Dsum, FF,
            (int)CROW, (int)CROW, NN, NN * CROW, NN * CROW, NN2);
        // 4) supT[o,m] = sup[m,o]/D[m]
        scale_transpose<<<dim3(NN / 32, FF / 32, BB), blk, 0, stream>>>(Call, Dsum, supT, 0);
        // 5) out[n,o] = E[n,:]·supT[o,:] + bias[o] — (2,8,8) = 128 blocks
        gemm256<0><<<dim3(FF / 256, NN / 256, BB), blk5, 0, stream>>>(
            E, supT, out, bias, nullptr, NN,
            NN, NN, FF, NN2, NF, NF);
    } else {
        for (int b = 0; b < BB; ++b) {
            const unsigned short* Cb = Call + (size_t)b * NN * CROW;
            gemm256<2><<<dim3(NN / 256, NN / 256, 1), blk5, 0, stream>>>(
                Cb, Cb + FF, E, nullptr, Dsum + (size_t)b * NN, FF,
                (int)CROW, (int)CROW, NN, 0, 0, 0);
            scale_transpose<<<dim3(NN / 32, FF / 32, 1), blk, 0, stream>>>(Call, Dsum, supT, b);
            gemm256<0><<<dim3(FF / 256, NN / 256, 1), blk5, 0, stream>>>(
                E, supT + (size_t)b * NF, out + (size_t)b * NF, bias, nullptr, NN,
                NN, NN, FF, 0, 0, 0);
        }
    }
}

// Round 7
// 224.594 us; speedup vs baseline: 1.2066x; 1.0463x over previous
//
#include <hip/hip_runtime.h>
#include <math.h>

// B=8, N=2048, Fin=Fout=512, fp32 in/out. bf16 MFMA internally.
// Algebra: adj = X·(w1^T w2)·X^T  ->  precompute V = w2^T·w1 (512x512, scaled
// by log2e), Y = X·V^T (BT-GEMM vs V rows), E = exp2(Y·X^T), softmax over
// columns via D colsums, out = E·(sup/D) + bias.
#define BB 8
#define NN 2048
#define FF 512
#define LOG2E 1.4426950408889634f

typedef __attribute__((ext_vector_type(8))) short short8;
typedef __attribute__((ext_vector_type(4))) float floatx4;
typedef __attribute__((ext_vector_type(2))) float float2v;
typedef __attribute__((ext_vector_type(2))) __bf16 bf16x2;

__device__ __forceinline__ unsigned short f2bf(float f) {
    union { float f; unsigned u; } v; v.f = f;
    unsigned r = v.u + 0x7FFFu + ((v.u >> 16) & 1u);
    return (unsigned short)(r >> 16);
}

__device__ __forceinline__ float fexp2(float x) {
#if __has_builtin(__builtin_amdgcn_exp2f)
    return __builtin_amdgcn_exp2f(x);
#else
    return __expf(x * 0.69314718056f);
#endif
}

#define BAR() __builtin_amdgcn_s_barrier()
#define LGKM0() do { asm volatile("s_waitcnt lgkmcnt(0)" ::: "memory"); \
                     __builtin_amdgcn_sched_barrier(0); } while (0)
#define GLDS(src, dst) __builtin_amdgcn_global_load_lds( \
    (const __attribute__((address_space(1))) void*)(src), \
    (__attribute__((address_space(3))) void*)(dst), 16, 0, 0)
#define VMW(n) asm volatile("s_waitcnt vmcnt(" #n ")" ::: "memory")

// ---------------------------------------------------------------------------
// 8-phase BT-GEMM (r6 core, M-templated): C[i,j] = sum_k A[i*a_ld+k]*B[j*b_ld+k]
// Tile BM x 256 (BM = M_REP*32), 512 thr = 8 waves (2M x 4N); wave tile
// (M_REP*16) x 64, acc[M_REP][4]. BK=64 in two 32-k halves; 4 rotating LDS
// slots per matrix [khalf][parity]. LDS: M_REP=8 -> 128 KB, M_REP=4 -> 96 KB.
// Phase p: { ds_read p's frags | stage ONE half | vmcnt(2LA+2)@ph4/8 |
//            s_barrier | lgkmcnt(0)+sched0 | setprio 16/8-MFMA setprio |
//            s_barrier }   (counted vmcnt never 0 mid-loop; ledger in r6)
// LA = BM/128 loads/thread per A stage; B stage = 2. Steady VMW = 2*LA+2.
// LDS chunk-XOR swizzle (counter-verified 0 conflicts r2-r6).
// Epilogue modes 1/2: LDS-restage + coalesced short8 readout (r4: WRITE/2).
// XCD flat-bijective swizzle, guarded for grids < 8 blocks.
// modes: 0 = fp32 out + bias[j]; 1 = bf16 out; 2 = bf16 exp2(out) + Dsum.
// Requires K % 128 == 0, K >= 256; grid.x*BN==Nc, grid.y*BM==M exactly.
// ---------------------------------------------------------------------------
template<int M_REP, int MODE>
__global__ __launch_bounds__(512) void gemm256(
    const unsigned short* __restrict__ A, const unsigned short* __restrict__ B,
    void* __restrict__ Cv, const float* __restrict__ bias, float* __restrict__ Dsum,
    int K, int a_ld, int b_ld, int ldc,
    long a_batch, long b_batch, long c_batch)
{
    constexpr int BM    = M_REP * 32;
    constexpr int LA    = BM / 128;          // loads/thread per A half-stage
    constexpr int ASLOT = BM * 32;
    constexpr int BSLOT = 256 * 32;
    __shared__ __align__(16) unsigned short SH[4 * ASLOT + 4 * BSLOT];

    const int tid  = threadIdx.x;
    const int wave = tid >> 6;
    const int lane = tid & 63;
    const int wr   = wave >> 2;              // 0..1 (M)
    const int wc   = wave & 3;               // 0..3 (N)
    const int fl   = lane & 15;
    const int quad = lane >> 4;

    // XCD-bijective block swizzle (skip when grid < 8 blocks)
    const int gx = gridDim.x, gy = gridDim.y;
    int flat = blockIdx.x + gx * (blockIdx.y + gy * blockIdx.z);
    const int cpx = (gx * gy * gridDim.z) >> 3;
    if (cpx > 0) flat = (flat & 7) * cpx + (flat >> 3);
    const int bx = flat % gx;
    const int rest = flat / gx;
    const int by = rest % gy;
    const int bz = rest / gy;

    const int m0 = by * BM;
    const int n0 = bx * 256;

    const unsigned short* Aptr = A + (long)bz * a_batch + (long)m0 * a_ld;
    const unsigned short* Bptr = B + (long)bz * b_batch + (long)n0 * b_ld;

    // staging source offsets (inverse-swizzled)
    int offA[LA], offB[2];
    #pragma unroll
    for (int i = 0; i < LA; ++i) {
        const int cl = i * 512 + tid;
        const int r = cl >> 2, s = cl & 3;
        offA[i] = r * a_ld + (s ^ ((r >> 1) & 3)) * 8;
    }
    #pragma unroll
    for (int i = 0; i < 2; ++i) {
        const int cl = i * 512 + tid;
        const int r = cl >> 2, s = cl & 3;
        offB[i] = r * b_ld + (s ^ ((r >> 1) & 3)) * 8;
    }

    // fragment ds_read bases: row = base+fl, chunk = quad^((fl>>1)&3)
    const int swz = (quad ^ ((fl >> 1) & 3)) * 8;
    const int aRd = (wr * (M_REP * 16) + fl) * 32 + swz;
    const int bRd = (wc * 64 + fl) * 32 + swz;

    auto sA = [&](int kh, int db, int kb) {
        #pragma unroll
        for (int i = 0; i < LA; ++i)
            GLDS(Aptr + kb + offA[i], &SH[(kh * 2 + db) * ASLOT + (i * 512 + tid) * 8]);
    };
    auto sB = [&](int kh, int db, int kb) {
        #pragma unroll
        for (int i = 0; i < 2; ++i)
            GLDS(Bptr + kb + offB[i], &SH[4 * ASLOT + (kh * 2 + db) * BSLOT + (i * 512 + tid) * 8]);
    };

    floatx4 acc[M_REP][4] = {};
    short8 af[M_REP], bf[2];

    auto RA = [&](int kh, int db) {
        const unsigned short* b = &SH[(kh * 2 + db) * ASLOT + aRd];
        #pragma unroll
        for (int m = 0; m < M_REP; ++m) af[m] = *(const short8*)(b + m * 512);
    };
    auto RB = [&](int kh, int db, int nh) {
        const unsigned short* b = &SH[4 * ASLOT + (kh * 2 + db) * BSLOT + bRd + nh * 1024];
        bf[0] = *(const short8*)(b);
        bf[1] = *(const short8*)(b + 512);
    };
    auto MC = [&](int nh) {
        __builtin_amdgcn_s_setprio(1);
        #pragma unroll
        for (int m = 0; m < M_REP; ++m) {
            acc[m][nh * 2]     = __builtin_amdgcn_mfma_f32_16x16x32_bf16(af[m], bf[0], acc[m][nh * 2], 0, 0, 0);
            acc[m][nh * 2 + 1] = __builtin_amdgcn_mfma_f32_16x16x32_bf16(af[m], bf[1], acc[m][nh * 2 + 1], 0, 0, 0);
        }
        __builtin_amdgcn_s_setprio(0);
    };

    const int nt = K >> 6;
    const int ni = nt >> 1;

    // prologue: tiles 0,1 minus Bk1(1); drain tile 0, keep 2LA+2 in flight
    sA(0, 0, 0);  sB(0, 0, 0);  sA(1, 0, 32); sB(1, 0, 32);
    sA(0, 1, 64); sB(0, 1, 64); sA(1, 1, 96);
    if constexpr (LA == 2) VMW(6); else VMW(4);
    BAR();

    for (int i = 0; i < ni; ++i) {
        const bool last = (i == ni - 1);
        const int kb1 = (2 * i + 1) * 64, kb2 = kb1 + 64, kb3 = kb2 + 64;

        // ph1: Q(t,k0,n01); stage Bk1(t+1)
        RA(0, 0); RB(0, 0, 0);
        sB(1, 1, kb1 + 32);
        BAR(); LGKM0(); MC(0); BAR();
        // ph2: Q(t,k0,n23); stage Ak0(t+2)
        RB(0, 0, 1);
        if (!last) sA(0, 0, kb2);
        BAR(); LGKM0(); MC(1); BAR();
        // ph3: Q(t,k1,n01); stage Bk0(t+2)
        RA(1, 0); RB(1, 0, 0);
        if (!last) sB(0, 0, kb2);
        BAR(); LGKM0(); MC(0); BAR();
        // ph4: Q(t,k1,n23); stage Ak1(t+2); drain through tile t+1
        RB(1, 0, 1);
        if (!last) {
            sA(1, 0, kb2 + 32);
            if constexpr (LA == 2) VMW(6); else VMW(4);
        } else {
            VMW(0);
        }
        BAR(); LGKM0(); MC(1); BAR();
        // ph5: Q(t+1,k0,n01); stage Bk1(t+2)
        RA(0, 1); RB(0, 1, 0);
        if (!last) sB(1, 0, kb2 + 32);
        BAR(); LGKM0(); MC(0); BAR();
        // ph6: Q(t+1,k0,n23); stage Ak0(t+3)
        RB(0, 1, 1);
        if (!last) sA(0, 1, kb3);
        BAR(); LGKM0(); MC(1); BAR();
        // ph7: Q(t+1,k1,n01); stage Bk0(t+3)
        RA(1, 1); RB(1, 1, 0);
        if (!last) sB(0, 1, kb3);
        BAR(); LGKM0(); MC(0); BAR();
        // ph8: Q(t+1,k1,n23); stage Ak1(t+3); drain through tile t+2
        RB(1, 1, 1);
        if (!last) {
            sA(1, 1, kb3 + 32);
            if constexpr (LA == 2) VMW(6); else VMW(4);
        }
        BAR(); LGKM0(); MC(1); BAR();
    }

    const int wmg = m0 + wr * (M_REP * 16);
    const int wcol = wc * 64;

    if constexpr (MODE == 0) {
        float* Cb = (float*)Cv + (long)bz * c_batch;
        #pragma unroll
        for (int n = 0; n < 4; ++n) {
            const int ng = n0 + wcol + n * 16 + fl;
            const float badd = bias ? bias[ng] : 0.0f;
            #pragma unroll
            for (int m = 0; m < M_REP; ++m) {
                const int mg = wmg + m * 16 + quad * 4;
                #pragma unroll
                for (int r = 0; r < 4; ++r)
                    Cb[(long)(mg + r) * ldc + ng] = acc[m][n][r] + badd;
            }
        }
    } else {
        // modes 1/2: LDS-restage the BM x 256 bf16 tile, coalesced readout.
        unsigned short* Cb = (unsigned short*)Cv + (long)bz * c_batch;
        if constexpr (MODE == 2) {
            float* Db = Dsum + (long)bz * NN;
            #pragma unroll
            for (int m = 0; m < M_REP; ++m)
                #pragma unroll
                for (int n = 0; n < 4; ++n)
                    #pragma unroll
                    for (int r = 0; r < 4; ++r)
                        acc[m][n][r] = fexp2(acc[m][n][r]);
            #pragma unroll
            for (int n = 0; n < 4; ++n) {
                float csum = 0.f;
                #pragma unroll
                for (int m = 0; m < M_REP; ++m)
                    csum += acc[m][n][0] + acc[m][n][1] + acc[m][n][2] + acc[m][n][3];
                csum += __shfl_xor(csum, 16);
                csum += __shfl_xor(csum, 32);
                if (quad == 0) atomicAdd(&Db[n0 + wcol + n * 16 + fl], csum);
            }
        }
        __syncthreads();
        // write: SH[row][col ^ (quad<<4)]  ((row>>2)&3 == quad)
        #pragma unroll
        for (int m = 0; m < M_REP; ++m) {
            const int rowb = wr * (M_REP * 16) + m * 16 + quad * 4;
            #pragma unroll
            for (int n = 0; n < 4; ++n) {
                const int pc = (wcol + n * 16 + fl) ^ (quad << 4);
                #pragma unroll
                for (int r = 0; r < 4; ++r)
                    SH[(rowb + r) * 256 + pc] = f2bf(acc[m][n][r]);
            }
        }
        __syncthreads();
        // coalesced readout: short8 per thread, dwordx4 store
        #pragma unroll
        for (int k = 0; k < M_REP * 2; ++k) {
            const int idx = k * 512 + tid;
            const int row = idx >> 5, c8 = (idx & 31) * 8;
            const int lcol = c8 ^ (((row >> 2) & 3) << 4);
            short8 vv = *(const short8*)&SH[row * 256 + lcol];
            *(short8*)&Cb[(long)(m0 + row) * ldc + n0 + c8] = vv;
        }
    }
}

// fp32 -> bf16 vectorized convert of x
__global__ __launch_bounds__(256) void convert_x(
    const float* __restrict__ x, unsigned short* __restrict__ xb)
{
    const long i = ((long)blockIdx.x * 256 + threadIdx.x) * 8;
    float4 a = *(const float4*)(x + i);
    float4 b = *(const float4*)(x + i + 4);
    union { bf16x2 h[4]; short8 s8; } u;
    float2v v;
    v.x = a.x; v.y = a.y; u.h[0] = __builtin_convertvector(v, bf16x2);
    v.x = a.z; v.y = a.w; u.h[1] = __builtin_convertvector(v, bf16x2);
    v.x = b.x; v.y = b.y; u.h[2] = __builtin_convertvector(v, bf16x2);
    v.x = b.z; v.y = b.w; u.h[3] = __builtin_convertvector(v, bf16x2);
    *(short8*)(xb + i) = u.s8;
}

// out[o,f] = bf16(sc * in[f,o]) for dim x dim fp32 (dim % 32 == 0)
__global__ __launch_bounds__(256) void transpose_convert(
    const float* __restrict__ in, unsigned short* __restrict__ out, int dim, float sc)
{
    __shared__ float t[32][33];
    const int tx = threadIdx.x & 31, ty = threadIdx.x >> 5;
    const int x0 = blockIdx.x * 32, y0 = blockIdx.y * 32;
    #pragma unroll
    for (int k = 0; k < 32; k += 8)
        t[ty + k][tx] = in[(long)(y0 + ty + k) * dim + x0 + tx];
    __syncthreads();
    #pragma unroll
    for (int k = 0; k < 32; k += 8)
        out[(long)(x0 + ty + k) * dim + y0 + tx] = f2bf(t[tx][ty + k] * sc);
}

__global__ __launch_bounds__(256) void zero_f32(float* __restrict__ p, long n)
{
    long i = (long)blockIdx.x * 256 + threadIdx.x;
    if (i < n) p[i] = 0.0f;
}

// supT[o,m] = bf16( sup[m,o] / D[m] ); sup[m,o] = Call[m*1024 + 512 + o] (bf16).
__global__ __launch_bounds__(256) void scale_transpose(
    const unsigned short* __restrict__ Call, const float* __restrict__ D,
    unsigned short* __restrict__ supT, int batch0)
{
    __shared__ float t[32][33];
    __shared__ float rD[32];
    const int tx = threadIdx.x & 31, ty = threadIdx.x >> 5;
    const int mt = blockIdx.x * 32, ot = blockIdx.y * 32;
    const int b = batch0 + blockIdx.z;
    const unsigned short* Cb = Call + (long)b * NN * 1024;
    unsigned short* Tb = supT + (long)b * NN * FF;
    if (threadIdx.x < 32) rD[threadIdx.x] = 1.0f / D[(long)b * NN + mt + threadIdx.x];
    __syncthreads();
    #pragma unroll
    for (int k = 0; k < 32; k += 8) {
        unsigned short u = Cb[(long)(mt + ty + k) * 1024 + 512 + ot + tx];
        union { unsigned uu; float f; } cv; cv.uu = ((unsigned)u) << 16;
        t[ty + k][tx] = cv.f;
    }
    __syncthreads();
    #pragma unroll
    for (int k = 0; k < 32; k += 8)
        Tb[(long)(ot + ty + k) * NN + mt + tx] = f2bf(t[tx][ty + k] * rD[tx]);
}

extern "C" void kernel_launch(void* const* d_in, const int* in_sizes, int n_in,
                              void* d_out, int out_size, void* d_ws, size_t ws_size,
                              hipStream_t stream)
{
    const float* x      = (const float*)d_in[0];
    const float* weight = (const float*)d_in[1];
    const float* bias   = (const float*)d_in[2];
    const float* w_one  = (const float*)d_in[3];
    const float* w_two  = (const float*)d_in[4];
    float* out = (float*)d_out;

    const long NF  = (long)NN * FF;      // 1,048,576
    const long NN2 = (long)NN * NN;      // 4,194,304
    const long CROW = 1024;              // C_all row stride (Y | sup)

    // workspace carve
    char* p = (char*)d_ws;
    unsigned short* xb    = (unsigned short*)p; p += (size_t)BB * NF * 2;          // 16 MB
    unsigned short* Wg1   = (unsigned short*)p; p += (size_t)1024 * FF * 2;        // 1 MB  [V ; wT]
    unsigned short* w1T   = (unsigned short*)p; p += (size_t)FF * FF * 2;          // 0.5 MB
    unsigned short* w2T   = (unsigned short*)p; p += (size_t)FF * FF * 2;          // 0.5 MB
    unsigned short* Call  = (unsigned short*)p; p += (size_t)BB * NN * CROW * 2;   // 32 MB
    unsigned short* supT  = (unsigned short*)p; p += (size_t)BB * NF * 2;          // 16 MB
    float*          Dsum  = (float*)p;          p += (size_t)BB * NN * 4;          // 64 KB
    unsigned short* E     = (unsigned short*)p;                                    // 64 MB (full) or 8 MB (batch)
    unsigned short* Vw  = Wg1;                       // rows 0..511: V = w2^T·w1·log2e
    unsigned short* wTb = Wg1 + (size_t)FF * FF;     // rows 512..1023: weight^T

    const size_t fixed = (size_t)(p - (char*)d_ws);
    const bool full = ws_size >= fixed + (size_t)BB * NN2 * 2;

    dim3 blk(256), blk5(512);

    // 1) converts: x -> bf16; w1T (scaled log2e), w2T, weight^T
    convert_x<<<dim3((unsigned)(BB * NF / (256 * 8))), blk, 0, stream>>>(x, xb);
    transpose_convert<<<dim3(FF / 32, FF / 32), blk, 0, stream>>>(w_one, w1T, FF, LOG2E);
    transpose_convert<<<dim3(FF / 32, FF / 32), blk, 0, stream>>>(w_two, w2T, FF, 1.0f);
    transpose_convert<<<dim3(FF / 32, FF / 32), blk, 0, stream>>>(weight, wTb, FF, 1.0f);
    zero_f32<<<dim3((BB * NN) / 256), blk, 0, stream>>>(Dsum, BB * NN);

    // 2) V[g,f] = sum_e w2[e,g]·w1[e,f]·log2e = w2T[g,:]·w1T[f,:]  (512³, 4 blocks)
    gemm256<8, 1><<<dim3(FF / 256, FF / 256, 1), blk5, 0, stream>>>(
        w2T, w1T, Vw, nullptr, nullptr, FF,
        FF, FF, FF, 0, 0, 0);

    // 3) Call[n,:] = [ Y = X·V^T | sup = X·W ] : A = xb, B = [V ; wT] rows.
    //    grid (4,8,8) = 256 blocks = 1 exact CU round
    gemm256<8, 1><<<dim3(1024 / 256, NN / 256, BB), blk5, 0, stream>>>(
        xb, Wg1, Call, nullptr, nullptr, FF,
        FF, FF, (int)CROW, NF, 0, NN * CROW);

    if (full) {
        // 4) E[n,m] = exp2(Y[n,:]·X[m,:]); Dsum colsums. (8,8,8) = 512 blocks
        gemm256<8, 2><<<dim3(NN / 256, NN / 256, BB), blk5, 0, stream>>>(
            Call, xb, E, nullptr, Dsum, FF,
            (int)CROW, FF, NN, NN * CROW, NF, NN2);
        // 5) supT[o,m] = sup[m,o]/D[m]
        scale_transpose<<<dim3(NN / 32, FF / 32, BB), blk, 0, stream>>>(Call, Dsum, supT, 0);
        // 6) out = E·supT + bias : BM=128, grid (2,16,8) = 256 = 1 exact round
        gemm256<4, 0><<<dim3(FF / 256, NN / 128, BB), blk5, 0, stream>>>(
            E, supT, out, bias, nullptr, NN,
            NN, NN, FF, NN2, NF, NF);
    } else {
        for (int b = 0; b < BB; ++b) {
            const unsigned short* Cb = Call + (size_t)b * NN * CROW;
            gemm256<8, 2><<<dim3(NN / 256, NN / 256, 1), blk5, 0, stream>>>(
                Cb, xb + (size_t)b * NF, E, nullptr, Dsum + (size_t)b * NN, FF,
                (int)CROW, FF, NN, 0, 0, 0);
            scale_transpose<<<dim3(NN / 32, FF / 32, 1), blk, 0, stream>>>(Call, Dsum, supT, b);
            gemm256<4, 0><<<dim3(FF / 256, NN / 128, 1), blk5, 0, stream>>>(
                E, supT + (size_t)b * NF, out + (size_t)b * NF, bias, nullptr, NN,
                NN, NN, FF, 0, 0, 0);
        }
    }
}

// Round 8
// 214.402 us; speedup vs baseline: 1.2640x; 1.0475x over previous
//
#include <hip/hip_runtime.h>
#include <math.h>

// B=8, N=2048, Fin=Fout=512, fp32 in/out. bf16 MFMA internally.
// Algebra: adj = X·(w1^T w2)·X^T  ->  precompute V = w2^T·w1 (512x512, scaled
// by log2e), Y = X·V^T, E = exp2(Y·X^T), column-softmax via D colsums,
// out = E·(sup/D) + bias.
#define BB 8
#define NN 2048
#define FF 512
#define LOG2E 1.4426950408889634f

typedef __attribute__((ext_vector_type(8))) short short8;
typedef __attribute__((ext_vector_type(4))) float floatx4;
typedef __attribute__((ext_vector_type(2))) float float2v;
typedef __attribute__((ext_vector_type(2))) __bf16 bf16x2;

__device__ __forceinline__ unsigned short f2bf(float f) {
    union { float f; unsigned u; } v; v.f = f;
    unsigned r = v.u + 0x7FFFu + ((v.u >> 16) & 1u);
    return (unsigned short)(r >> 16);
}

__device__ __forceinline__ float fexp2(float x) {
#if __has_builtin(__builtin_amdgcn_exp2f)
    return __builtin_amdgcn_exp2f(x);
#else
    return __expf(x * 0.69314718056f);
#endif
}

__device__ __forceinline__ void pk_store(unsigned short* p0, unsigned short* p1,
                                         float a, float b) {
    union { bf16x2 h; unsigned short s[2]; } u;
    float2v v; v.x = a; v.y = b;
    u.h = __builtin_convertvector(v, bf16x2);
    *p0 = u.s[0]; *p1 = u.s[1];
}

#define BAR() __builtin_amdgcn_s_barrier()
#define LGKM0() do { asm volatile("s_waitcnt lgkmcnt(0)" ::: "memory"); \
                     __builtin_amdgcn_sched_barrier(0); } while (0)
#define GLDS(src, dst) __builtin_amdgcn_global_load_lds( \
    (const __attribute__((address_space(1))) void*)(src), \
    (__attribute__((address_space(3))) void*)(dst), 16, 0, 0)
#define VMW(n) asm volatile("s_waitcnt vmcnt(" #n ")" ::: "memory")

// ---------------------------------------------------------------------------
// 8-phase BT-GEMM (r7 core, unchanged): C[i,j] = sum_k A[i*a_ld+k]*B[j*b_ld+k]
// Tile BM x 256 (BM = M_REP*32), 512 thr = 8 waves (2M x 4N).
// modes: 0 = fp32 out + bias[j]; 1 = bf16 out; 2 = bf16 exp2(out) + Dsum.
// Requires K % 128 == 0, K >= 256; exact grid tiling.
// ---------------------------------------------------------------------------
template<int M_REP, int MODE>
__global__ __launch_bounds__(512) void gemm256(
    const unsigned short* __restrict__ A, const unsigned short* __restrict__ B,
    void* __restrict__ Cv, const float* __restrict__ bias, float* __restrict__ Dsum,
    int K, int a_ld, int b_ld, int ldc,
    long a_batch, long b_batch, long c_batch)
{
    constexpr int BM    = M_REP * 32;
    constexpr int LA    = BM / 128;
    constexpr int ASLOT = BM * 32;
    constexpr int BSLOT = 256 * 32;
    __shared__ __align__(16) unsigned short SH[4 * ASLOT + 4 * BSLOT];

    const int tid  = threadIdx.x;
    const int wave = tid >> 6;
    const int lane = tid & 63;
    const int wr   = wave >> 2;
    const int wc   = wave & 3;
    const int fl   = lane & 15;
    const int quad = lane >> 4;

    const int gx = gridDim.x, gy = gridDim.y;
    int flat = blockIdx.x + gx * (blockIdx.y + gy * blockIdx.z);
    const int cpx = (gx * gy * gridDim.z) >> 3;
    if (cpx > 0) flat = (flat & 7) * cpx + (flat >> 3);
    const int bx = flat % gx;
    const int rest = flat / gx;
    const int by = rest % gy;
    const int bz = rest / gy;

    const int m0 = by * BM;
    const int n0 = bx * 256;

    const unsigned short* Aptr = A + (long)bz * a_batch + (long)m0 * a_ld;
    const unsigned short* Bptr = B + (long)bz * b_batch + (long)n0 * b_ld;

    int offA[LA], offB[2];
    #pragma unroll
    for (int i = 0; i < LA; ++i) {
        const int cl = i * 512 + tid;
        const int r = cl >> 2, s = cl & 3;
        offA[i] = r * a_ld + (s ^ ((r >> 1) & 3)) * 8;
    }
    #pragma unroll
    for (int i = 0; i < 2; ++i) {
        const int cl = i * 512 + tid;
        const int r = cl >> 2, s = cl & 3;
        offB[i] = r * b_ld + (s ^ ((r >> 1) & 3)) * 8;
    }

    const int swz = (quad ^ ((fl >> 1) & 3)) * 8;
    const int aRd = (wr * (M_REP * 16) + fl) * 32 + swz;
    const int bRd = (wc * 64 + fl) * 32 + swz;

    auto sA = [&](int kh, int db, int kb) {
        #pragma unroll
        for (int i = 0; i < LA; ++i)
            GLDS(Aptr + kb + offA[i], &SH[(kh * 2 + db) * ASLOT + (i * 512 + tid) * 8]);
    };
    auto sB = [&](int kh, int db, int kb) {
        #pragma unroll
        for (int i = 0; i < 2; ++i)
            GLDS(Bptr + kb + offB[i], &SH[4 * ASLOT + (kh * 2 + db) * BSLOT + (i * 512 + tid) * 8]);
    };

    floatx4 acc[M_REP][4] = {};
    short8 af[M_REP], bf[2];

    auto RA = [&](int kh, int db) {
        const unsigned short* b = &SH[(kh * 2 + db) * ASLOT + aRd];
        #pragma unroll
        for (int m = 0; m < M_REP; ++m) af[m] = *(const short8*)(b + m * 512);
    };
    auto RB = [&](int kh, int db, int nh) {
        const unsigned short* b = &SH[4 * ASLOT + (kh * 2 + db) * BSLOT + bRd + nh * 1024];
        bf[0] = *(const short8*)(b);
        bf[1] = *(const short8*)(b + 512);
    };
    auto MC = [&](int nh) {
        __builtin_amdgcn_s_setprio(1);
        #pragma unroll
        for (int m = 0; m < M_REP; ++m) {
            acc[m][nh * 2]     = __builtin_amdgcn_mfma_f32_16x16x32_bf16(af[m], bf[0], acc[m][nh * 2], 0, 0, 0);
            acc[m][nh * 2 + 1] = __builtin_amdgcn_mfma_f32_16x16x32_bf16(af[m], bf[1], acc[m][nh * 2 + 1], 0, 0, 0);
        }
        __builtin_amdgcn_s_setprio(0);
    };

    const int nt = K >> 6;
    const int ni = nt >> 1;

    sA(0, 0, 0);  sB(0, 0, 0);  sA(1, 0, 32); sB(1, 0, 32);
    sA(0, 1, 64); sB(0, 1, 64); sA(1, 1, 96);
    if constexpr (LA == 2) VMW(6); else VMW(4);
    BAR();

    for (int i = 0; i < ni; ++i) {
        const bool last = (i == ni - 1);
        const int kb1 = (2 * i + 1) * 64, kb2 = kb1 + 64, kb3 = kb2 + 64;

        RA(0, 0); RB(0, 0, 0);
        sB(1, 1, kb1 + 32);
        BAR(); LGKM0(); MC(0); BAR();

        RB(0, 0, 1);
        if (!last) sA(0, 0, kb2);
        BAR(); LGKM0(); MC(1); BAR();

        RA(1, 0); RB(1, 0, 0);
        if (!last) sB(0, 0, kb2);
        BAR(); LGKM0(); MC(0); BAR();

        RB(1, 0, 1);
        if (!last) {
            sA(1, 0, kb2 + 32);
            if constexpr (LA == 2) VMW(6); else VMW(4);
        } else {
            VMW(0);
        }
        BAR(); LGKM0(); MC(1); BAR();

        RA(0, 1); RB(0, 1, 0);
        if (!last) sB(1, 0, kb2 + 32);
        BAR(); LGKM0(); MC(0); BAR();

        RB(0, 1, 1);
        if (!last) sA(0, 1, kb3);
        BAR(); LGKM0(); MC(1); BAR();

        RA(1, 1); RB(1, 1, 0);
        if (!last) sB(0, 1, kb3);
        BAR(); LGKM0(); MC(0); BAR();

        RB(1, 1, 1);
        if (!last) {
            sA(1, 1, kb3 + 32);
            if constexpr (LA == 2) VMW(6); else VMW(4);
        }
        BAR(); LGKM0(); MC(1); BAR();
    }

    const int wmg = m0 + wr * (M_REP * 16);
    const int wcol = wc * 64;

    if constexpr (MODE == 0) {
        float* Cb = (float*)Cv + (long)bz * c_batch;
        #pragma unroll
        for (int n = 0; n < 4; ++n) {
            const int ng = n0 + wcol + n * 16 + fl;
            const float badd = bias ? bias[ng] : 0.0f;
            #pragma unroll
            for (int m = 0; m < M_REP; ++m) {
                const int mg = wmg + m * 16 + quad * 4;
                #pragma unroll
                for (int r = 0; r < 4; ++r)
                    Cb[(long)(mg + r) * ldc + ng] = acc[m][n][r] + badd;
            }
        }
    } else {
        unsigned short* Cb = (unsigned short*)Cv + (long)bz * c_batch;
        if constexpr (MODE == 2) {
            float* Db = Dsum + (long)bz * NN;
            #pragma unroll
            for (int m = 0; m < M_REP; ++m)
                #pragma unroll
                for (int n = 0; n < 4; ++n)
                    #pragma unroll
                    for (int r = 0; r < 4; ++r)
                        acc[m][n][r] = fexp2(acc[m][n][r]);
            #pragma unroll
            for (int n = 0; n < 4; ++n) {
                float csum = 0.f;
                #pragma unroll
                for (int m = 0; m < M_REP; ++m)
                    csum += acc[m][n][0] + acc[m][n][1] + acc[m][n][2] + acc[m][n][3];
                csum += __shfl_xor(csum, 16);
                csum += __shfl_xor(csum, 32);
                if (quad == 0) atomicAdd(&Db[n0 + wcol + n * 16 + fl], csum);
            }
        }
        __syncthreads();
        #pragma unroll
        for (int m = 0; m < M_REP; ++m) {
            const int rowb = wr * (M_REP * 16) + m * 16 + quad * 4;
            #pragma unroll
            for (int n = 0; n < 4; ++n) {
                const int pc = (wcol + n * 16 + fl) ^ (quad << 4);
                #pragma unroll
                for (int r = 0; r < 4; ++r)
                    SH[(rowb + r) * 256 + pc] = f2bf(acc[m][n][r]);
            }
        }
        __syncthreads();
        #pragma unroll
        for (int k = 0; k < M_REP * 2; ++k) {
            const int idx = k * 512 + tid;
            const int row = idx >> 5, c8 = (idx & 31) * 8;
            const int lcol = c8 ^ (((row >> 2) & 3) << 4);
            short8 vv = *(const short8*)&SH[row * 256 + lcol];
            *(short8*)&Cb[(long)(m0 + row) * ldc + n0 + c8] = vv;
        }
    }
}

// ---------------------------------------------------------------------------
// Small 128x128-tile BT-GEMM (r0 verified core), bf16 out. For V = w2T·w1T^T:
// 512x512x512 on 16 blocks (~16 CUs) instead of 4 gemm256 blocks (~26us serial).
// ---------------------------------------------------------------------------
__global__ __launch_bounds__(256) void gemm128_bt(
    const unsigned short* __restrict__ A, const unsigned short* __restrict__ B,
    unsigned short* __restrict__ C, int K, int a_ld, int b_ld, int ldc)
{
    __shared__ __align__(16) unsigned short Alds[128 * 64];
    __shared__ __align__(16) unsigned short Blds[128 * 64];

    const int tid  = threadIdx.x;
    const int wave = tid >> 6;
    const int lane = tid & 63;
    const int m0 = blockIdx.y * 128;
    const int n0 = blockIdx.x * 128;

    const unsigned short* Aptr = A + (long)m0 * a_ld;
    const unsigned short* Bptr = B + (long)n0 * b_ld;

    const int wm   = (wave >> 1) * 64;
    const int wn   = (wave & 1) * 64;
    const int fl   = lane & 15;
    const int quad = lane >> 4;

    int offA[4], offB[4], cb[4];
    #pragma unroll
    for (int issue = 0; issue < 4; ++issue) {
        const int cbase = issue * 256 + wave * 64;
        const int c = cbase + lane;
        const int row = c >> 3;
        const int kq = ((c & 7) ^ ((c >> 3) & 7)) * 8;
        offA[issue] = row * a_ld + kq;
        offB[issue] = row * b_ld + kq;
        cb[issue] = cbase * 8;
    }

    floatx4 acc[4][4] = {};

    for (int k0 = 0; k0 < K; k0 += 64) {
        #pragma unroll
        for (int issue = 0; issue < 4; ++issue) {
            GLDS(Aptr + offA[issue], &Alds[cb[issue] + lane * 8]);
            GLDS(Bptr + offB[issue], &Blds[cb[issue] + lane * 8]);
        }
        Aptr += 64; Bptr += 64;
        __syncthreads();

        #pragma unroll
        for (int s = 0; s < 2; ++s) {
            short8 af[4], bfr[4];
            const int slot = ((s * 4 + quad) ^ (fl & 7)) * 8;
            #pragma unroll
            for (int i = 0; i < 4; ++i)
                af[i] = *(const short8*)&Alds[(wm + i * 16 + fl) * 64 + slot];
            #pragma unroll
            for (int j = 0; j < 4; ++j)
                bfr[j] = *(const short8*)&Blds[(wn + j * 16 + fl) * 64 + slot];
            #pragma unroll
            for (int i = 0; i < 4; ++i)
                #pragma unroll
                for (int j = 0; j < 4; ++j)
                    acc[i][j] = __builtin_amdgcn_mfma_f32_16x16x32_bf16(af[i], bfr[j], acc[i][j], 0, 0, 0);
        }
        __syncthreads();
    }

    #pragma unroll
    for (int j = 0; j < 4; ++j) {
        const int ng = n0 + wn + j * 16 + fl;
        #pragma unroll
        for (int i = 0; i < 4; ++i) {
            const int mg = m0 + wm + i * 16 + quad * 4;
            pk_store(&C[(long)(mg + 0) * ldc + ng], &C[(long)(mg + 1) * ldc + ng],
                     acc[i][j][0], acc[i][j][1]);
            pk_store(&C[(long)(mg + 2) * ldc + ng], &C[(long)(mg + 3) * ldc + ng],
                     acc[i][j][2], acc[i][j][3]);
        }
    }
}

// ---------------------------------------------------------------------------
// Fused prep: [0,4096) x->bf16 | [4096,4864) three 512x512 transposes
// (w1*log2e, w2, weight) | [4864,4928) Dsum zero.  One dispatch.
// ---------------------------------------------------------------------------
__global__ __launch_bounds__(256) void prep_all(
    const float* __restrict__ x, const float* __restrict__ w1,
    const float* __restrict__ w2, const float* __restrict__ w,
    unsigned short* __restrict__ xb, unsigned short* __restrict__ w1T,
    unsigned short* __restrict__ w2T, unsigned short* __restrict__ wT,
    float* __restrict__ Dsum)
{
    __shared__ float tl[32][33];
    int b = blockIdx.x;
    if (b < 4096) {
        const long i = ((long)b * 256 + threadIdx.x) * 8;
        float4 a = *(const float4*)(x + i);
        float4 c = *(const float4*)(x + i + 4);
        union { bf16x2 h[4]; short8 s8; } u;
        float2v v;
        v.x = a.x; v.y = a.y; u.h[0] = __builtin_convertvector(v, bf16x2);
        v.x = a.z; v.y = a.w; u.h[1] = __builtin_convertvector(v, bf16x2);
        v.x = c.x; v.y = c.y; u.h[2] = __builtin_convertvector(v, bf16x2);
        v.x = c.z; v.y = c.w; u.h[3] = __builtin_convertvector(v, bf16x2);
        *(short8*)(xb + i) = u.s8;
        return;
    }
    b -= 4096;
    if (b < 768) {
        const float* in; unsigned short* out; float sc = 1.0f;
        const int seg = b >> 8, t = b & 255;
        if (seg == 0)      { in = w1; out = w1T; sc = LOG2E; }
        else if (seg == 1) { in = w2; out = w2T; }
        else               { in = w;  out = wT; }
        const int tx = threadIdx.x & 31, ty = threadIdx.x >> 5;
        const int x0 = (t & 15) * 32, y0 = (t >> 4) * 32;
        #pragma unroll
        for (int k = 0; k < 32; k += 8)
            tl[ty + k][tx] = in[(long)(y0 + ty + k) * FF + x0 + tx];
        __syncthreads();
        #pragma unroll
        for (int k = 0; k < 32; k += 8)
            out[(long)(x0 + ty + k) * FF + y0 + tx] = f2bf(tl[tx][ty + k] * sc);
        return;
    }
    b -= 768;
    Dsum[(long)b * 256 + threadIdx.x] = 0.0f;
}

// supT[o,m] = bf16( sup[m,o] / D[m] ); sup[m,o] = Call[m*1024 + 512 + o] (bf16).
__global__ __launch_bounds__(256) void scale_transpose(
    const unsigned short* __restrict__ Call, const float* __restrict__ D,
    unsigned short* __restrict__ supT, int batch0)
{
    __shared__ float t[32][33];
    __shared__ float rD[32];
    const int tx = threadIdx.x & 31, ty = threadIdx.x >> 5;
    const int mt = blockIdx.x * 32, ot = blockIdx.y * 32;
    const int b = batch0 + blockIdx.z;
    const unsigned short* Cb = Call + (long)b * NN * 1024;
    unsigned short* Tb = supT + (long)b * NN * FF;
    if (threadIdx.x < 32) rD[threadIdx.x] = 1.0f / D[(long)b * NN + mt + threadIdx.x];
    __syncthreads();
    #pragma unroll
    for (int k = 0; k < 32; k += 8) {
        unsigned short u = Cb[(long)(mt + ty + k) * 1024 + 512 + ot + tx];
        union { unsigned uu; float f; } cv; cv.uu = ((unsigned)u) << 16;
        t[ty + k][tx] = cv.f;
    }
    __syncthreads();
    #pragma unroll
    for (int k = 0; k < 32; k += 8)
        Tb[(long)(ot + ty + k) * NN + mt + tx] = f2bf(t[tx][ty + k] * rD[tx]);
}

extern "C" void kernel_launch(void* const* d_in, const int* in_sizes, int n_in,
                              void* d_out, int out_size, void* d_ws, size_t ws_size,
                              hipStream_t stream)
{
    const float* x      = (const float*)d_in[0];
    const float* weight = (const float*)d_in[1];
    const float* bias   = (const float*)d_in[2];
    const float* w_one  = (const float*)d_in[3];
    const float* w_two  = (const float*)d_in[4];
    float* out = (float*)d_out;

    const long NF  = (long)NN * FF;      // 1,048,576
    const long NN2 = (long)NN * NN;      // 4,194,304
    const long CROW = 1024;              // C_all row stride (Y | sup)

    // workspace carve
    char* p = (char*)d_ws;
    unsigned short* xb    = (unsigned short*)p; p += (size_t)BB * NF * 2;          // 16 MB
    unsigned short* Wg1   = (unsigned short*)p; p += (size_t)1024 * FF * 2;        // 1 MB  [V ; wT]
    unsigned short* w1T   = (unsigned short*)p; p += (size_t)FF * FF * 2;          // 0.5 MB
    unsigned short* w2T   = (unsigned short*)p; p += (size_t)FF * FF * 2;          // 0.5 MB
    unsigned short* Call  = (unsigned short*)p; p += (size_t)BB * NN * CROW * 2;   // 32 MB
    unsigned short* supT  = (unsigned short*)p; p += (size_t)BB * NF * 2;          // 16 MB
    float*          Dsum  = (float*)p;          p += (size_t)BB * NN * 4;          // 64 KB
    unsigned short* E     = (unsigned short*)p;                                    // 64 MB (full) or 8 MB (batch)
    unsigned short* Vw  = Wg1;                       // rows 0..511: V = w2^T·w1·log2e
    unsigned short* wTb = Wg1 + (size_t)FF * FF;     // rows 512..1023: weight^T

    const size_t fixed = (size_t)(p - (char*)d_ws);
    const bool full = ws_size >= fixed + (size_t)BB * NN2 * 2;

    dim3 blk(256), blk5(512);

    // 1) fused prep: x->bf16, w1T(log2e)/w2T/wT transposes, Dsum zero
    prep_all<<<dim3(4928), blk, 0, stream>>>(
        x, w_one, w_two, weight, xb, w1T, w2T, wTb, Dsum);

    // 2) V[g,f] = w2T[g,:]·w1T[f,:]  — 128² tiles, 16 blocks (~16 CUs)
    gemm128_bt<<<dim3(FF / 128, FF / 128), blk, 0, stream>>>(
        w2T, w1T, Vw, FF, FF, FF, FF);

    // 3) Call[n,:] = [ Y = X·V^T | sup = X·W ]  — (4,8,8) = 256 blocks, 1 round
    gemm256<8, 1><<<dim3(1024 / 256, NN / 256, BB), blk5, 0, stream>>>(
        xb, Wg1, Call, nullptr, nullptr, FF,
        FF, FF, (int)CROW, NF, 0, NN * CROW);

    if (full) {
        // 4) E[n,m] = exp2(Y[n,:]·X[m,:]); Dsum colsums. (8,8,8) = 512 blocks
        gemm256<8, 2><<<dim3(NN / 256, NN / 256, BB), blk5, 0, stream>>>(
            Call, xb, E, nullptr, Dsum, FF,
            (int)CROW, FF, NN, NN * CROW, NF, NN2);
        // 5) supT[o,m] = sup[m,o]/D[m]
        scale_transpose<<<dim3(NN / 32, FF / 32, BB), blk, 0, stream>>>(Call, Dsum, supT, 0);
        // 6) out = E·supT + bias : BM=128, (2,16,8) = 256 blocks, 1 round
        gemm256<4, 0><<<dim3(FF / 256, NN / 128, BB), blk5, 0, stream>>>(
            E, supT, out, bias, nullptr, NN,
            NN, NN, FF, NN2, NF, NF);
    } else {
        for (int b = 0; b < BB; ++b) {
            const unsigned short* Cb = Call + (size_t)b * NN * CROW;
            gemm256<8, 2><<<dim3(NN / 256, NN / 256, 1), blk5, 0, stream>>>(
                Cb, xb + (size_t)b * NF, E, nullptr, Dsum + (size_t)b * NN, FF,
                (int)CROW, FF, NN, 0, 0, 0);
            scale_transpose<<<dim3(NN / 32, FF / 32, 1), blk, 0, stream>>>(Call, Dsum, supT, b);
            gemm256<4, 0><<<dim3(FF / 256, NN / 128, 1), blk5, 0, stream>>>(
                E, supT + (size_t)b * NF, out + (size_t)b * NF, bias, nullptr, NN,
                NN, NN, FF, 0, 0, 0);
        }
    }
}